// Round 14
// baseline (1315.172 us; speedup 1.0000x reference)
//
#include <hip/hip_runtime.h>
#include <hip/hip_bf16.h>

typedef float f32x4 __attribute__((ext_vector_type(4)));
typedef short s16x8 __attribute__((ext_vector_type(8)));
typedef unsigned int u32;
typedef unsigned short u16;

#define DEV static __device__ __forceinline__

namespace {
constexpr int V = 32000, E = 256, H = 512, Z = 64, B = 32, T = 128;
constexpr u32 POISON = 0xFFFFFFFFu;
constexpr int GUARD = 1 << 20;

// ---- workspace layout (bytes); total extent 45,523,200 ----
constexpr size_t OFF_ZF   = 0;                          // fwd h slot 0 (zeros, 32KB)
constexpr size_t OFF_ZB   = 32768;                      // bwd h slot 0 (zeros, 32KB)
constexpr size_t OFF_PF   = 65536;                      // fwd h slots 1..128 (4MB)
constexpr size_t OFF_PB   = OFF_PF + (size_t)T * 32768; // bwd h slots (4MB)
constexpr size_t OFF_H0   = OFF_PB + (size_t)T * 32768; // dec h0 (32KB)
constexpr size_t OFF_HENC = OFF_H0 + 32768;             // h_enc (32KB)
constexpr size_t OFF_HS   = OFF_HENC + 32768;           // hs, T-MAJOR [t][b][H] bf16 (4MB)
constexpr size_t OFF_LGY  = OFF_HS + (size_t)B*T*H*2;   // 4096 f32
constexpr size_t OFF_CER  = OFF_LGY + 16384;            // 4096 f32
constexpr size_t OFF_PEND = OFF_CER + 16384;            // poison end
constexpr size_t OFF_Z    = OFF_PEND;                   // B*Z f32 (not poisoned)
constexpr size_t OFF_KLP  = OFF_Z + 8192;               // Z f32 (not poisoned)
constexpr size_t OFF_WB   = OFF_KLP + 256;              // V*H bf16 = 32,768,000
constexpr size_t OFF_CEP  = OFF_PF;                     // OVERLAY on enc fwd h-slots (dead in phaseB)
// CEP layout: [chunk ct][row r] float2 -> contiguous 128-row writes
}

DEV u16 f2b(float f) {
  u32 x = __builtin_bit_cast(u32, f);
  return (u16)((x + 0x7fffu + ((x >> 16) & 1u)) >> 16);
}
DEV float b2f(u16 u) {
  u32 x = ((u32)u) << 16;
  return __builtin_bit_cast(float, x);
}
DEV float fsig(float x) { return 1.f / (1.f + __expf(-x)); }
DEV float ftanh(float x) { return 2.f / (1.f + __expf(-2.f * x)) - 1.f; }

DEV u32 aload(const u32* p) { return __hip_atomic_load(p, __ATOMIC_RELAXED, __HIP_MEMORY_SCOPE_AGENT); }
DEV void astore(u32* p, u32 v) { __hip_atomic_store(p, v, __ATOMIC_RELAXED, __HIP_MEMORY_SCOPE_AGENT); }
DEV void afstore(u32* p, float v) { astore(p, __builtin_bit_cast(u32, v)); }

DEV u32* hslot(char* ws, int dir, int s) {
  size_t off = (s == 0) ? (dir ? OFF_ZB : OFF_ZF)
                        : ((dir ? OFF_PB : OFF_PF) + (size_t)(s - 1) * 32768);
  return reinterpret_cast<u32*>(ws + off);
}

// ===================================================================
// PHASE A: encoder (64 WGs) + out_W cast (128 WGs)   [192 WGs total]
// ===================================================================
__global__ __launch_bounds__(512, 1) void phaseA_k(
    const int* __restrict__ x, const float* __restrict__ emb,
    const float* __restrict__ fWih, const float* __restrict__ fWhh, const float* __restrict__ fb,
    const float* __restrict__ bWih, const float* __restrict__ bWhh, const float* __restrict__ bb,
    const float* __restrict__ enc_hW, const float* __restrict__ enc_hb,
    const float* __restrict__ mu_W, const float* __restrict__ mu_b,
    const float* __restrict__ std_W, const float* __restrict__ std_b,
    const float* __restrict__ epsv, const float* __restrict__ out_W,
    char* __restrict__ ws)
{
  __shared__ __align__(16) u16 Wl[64][776];      // weights (gate-interleaved rows)
  __shared__ __align__(16) u16 act[32][776];     // [b][emb(256) | h(512)]
  __shared__ __align__(16) float gates[64][33];  // tails only

  const int tid = threadIdx.x;
  const int wg = blockIdx.x;

  if (wg >= 64) {
    // ---------------- cast out_W -> bf16 (grid-stride, 128 WGs) ----------------
    const size_t total = (size_t)V * H / 8;   // 2,048,000
    for (size_t idx = (size_t)(wg - 64) * 512 + tid; idx < total; idx += (size_t)128 * 512) {
      const float4* src = reinterpret_cast<const float4*>(out_W + idx * 8);
      float4 a = src[0], b = src[1];
      s16x8 o;
      o[0] = (short)f2b(a.x); o[1] = (short)f2b(a.y); o[2] = (short)f2b(a.z); o[3] = (short)f2b(a.w);
      o[4] = (short)f2b(b.x); o[5] = (short)f2b(b.y); o[6] = (short)f2b(b.z); o[7] = (short)f2b(b.w);
      *reinterpret_cast<s16x8*>(ws + OFF_WB + idx * 16) = o;
    }
    return;
  }

  // ---------------- encoder LSTM ----------------
  const bool bwd = wg >= 32;
  const int dir = bwd ? 1 : 0;
  const int lw = wg & 31;
  const int u0 = lw * 16;
  const float* Wih = bwd ? bWih : fWih;
  const float* Whh = bwd ? bWhh : fWhh;
  const float* bv  = bwd ? bb : fb;

  // weights into LDS, GATE-INTERLEAVED rows: local row r -> unit (r>>2), gate (r&3)
  {
    int r = tid >> 3, s8 = tid & 7;
    int grow = (r & 3) * H + u0 + (r >> 2);
    for (int kc = s8 * 96; kc < s8 * 96 + 96; kc += 8) {
      const float4* p;
      if (kc < E) p = reinterpret_cast<const float4*>(Wih + (size_t)grow * E + kc);
      else        p = reinterpret_cast<const float4*>(Whh + (size_t)grow * H + (kc - E));
      float4 a = p[0], b4 = p[1];
      Wl[r][kc+0] = f2b(a.x);  Wl[r][kc+1] = f2b(a.y);  Wl[r][kc+2] = f2b(a.z);  Wl[r][kc+3] = f2b(a.w);
      Wl[r][kc+4] = f2b(b4.x); Wl[r][kc+5] = f2b(b4.y); Wl[r][kc+6] = f2b(b4.z); Wl[r][kc+7] = f2b(b4.w);
    }
  }

  const int ab = tid >> 4, au = tid & 15;   // emb-staging mapping
  const int wv = tid >> 6, lane = tid & 63, l15 = lane & 15, lhi = lane >> 4;
  const int mq = wv & 3, nh = wv >> 2;
  const int unit = u0 + mq * 4 + lhi;       // this thread's LSTM unit
  const int batch = nh * 16 + l15;          // this thread's batch
  const float Bi = bv[0*H + unit], Bf = bv[1*H + unit];
  const float Bg = bv[2*H + unit], Bo = bv[3*H + unit];
  float c = 0.f;
  u32* actu = reinterpret_cast<u32*>(&act[0][0]);

  auto stage_emb = [&](int t) {
    int tt = bwd ? (T - 1 - t) : t;
    const float* src = emb + (size_t)x[ab * T + tt] * E + au * 16;
    const float4* s4 = reinterpret_cast<const float4*>(src);
    float4 A0 = s4[0], A1 = s4[1], A2 = s4[2], A3 = s4[3];
    u32 w0 = f2b(A0.x) | ((u32)f2b(A0.y) << 16);
    u32 w1 = f2b(A0.z) | ((u32)f2b(A0.w) << 16);
    u32 w2 = f2b(A1.x) | ((u32)f2b(A1.y) << 16);
    u32 w3 = f2b(A1.z) | ((u32)f2b(A1.w) << 16);
    u32 w4 = f2b(A2.x) | ((u32)f2b(A2.y) << 16);
    u32 w5 = f2b(A2.z) | ((u32)f2b(A2.w) << 16);
    u32 w6 = f2b(A3.x) | ((u32)f2b(A3.y) << 16);
    u32 w7 = f2b(A3.z) | ((u32)f2b(A3.w) << 16);
    u32* dst = actu + ab * 388 + au * 8;
    reinterpret_cast<uint4*>(dst)[0] = make_uint4(w0, w1, w2, w3);
    reinterpret_cast<uint4*>(dst)[1] = make_uint4(w4, w5, w6, w7);
  };

  stage_emb(0);
  __syncthreads();

  const u16* wrow = &Wl[mq * 16 + l15][0];
  const u16* arow = &act[nh * 16 + l15][0];

  for (int t = 0; t < T; ++t) {
    f32x4 ac[4];
    #pragma unroll
    for (int i = 0; i < 4; ++i) ac[i] = {0, 0, 0, 0};

    // [A] issue coalesced h(t) loads (lanes consecutive -> 2KB/wave)
    const u32* hsrc = hslot(ws, dir, t);
    u32 tmp[16];
    #pragma unroll
    for (int j = 0; j < 16; ++j) tmp[j] = aload(hsrc + tid + j * 512);

    // [B] emb-part MFMA (K 0..255) under load/poll latency
    #pragma unroll
    for (int fe = 0; fe < 8; ++fe) {
      int kk = fe * 32 + lhi * 8;
      s16x8 A = *reinterpret_cast<const s16x8*>(wrow + kk);
      s16x8 Bv = *reinterpret_cast<const s16x8*>(arow + kk);
      ac[fe & 3] = __builtin_amdgcn_mfma_f32_16x16x32_bf16(A, Bv, ac[fe & 3], 0, 0, 0);
    }

    // [C] poll for data validity
    {
      int guard = 0;
      while (true) {
        bool bad = false;
        #pragma unroll
        for (int j = 0; j < 16; ++j)
          if (tmp[j] == POISON) { bad = true; tmp[j] = aload(hsrc + tid + j * 512); }
        if (!bad || ++guard > GUARD) break;
        __builtin_amdgcn_s_sleep(1);
      }
    }
    // [D] h -> LDS (disjoint from emb region)
    #pragma unroll
    for (int j = 0; j < 16; ++j) {
      int i = tid + j * 512;
      actu[(i >> 8) * 388 + 128 + (i & 255)] = tmp[j];
    }
    __syncthreads();   // [E] h ready; all emb MFMA reads done

    // [F] h-part MFMA (K 256..767) + in-register nonlinearity + h store
    {
      #pragma unroll
      for (int f = 0; f < 16; ++f) {
        int kk = 256 + f * 32 + lhi * 8;
        s16x8 A = *reinterpret_cast<const s16x8*>(wrow + kk);
        s16x8 Bv = *reinterpret_cast<const s16x8*>(arow + kk);
        ac[f & 3] = __builtin_amdgcn_mfma_f32_16x16x32_bf16(A, Bv, ac[f & 3], 0, 0, 0);
      }
      f32x4 acs = (ac[0] + ac[1]) + (ac[2] + ac[3]);
      float gi = acs[0] + Bi, gf = acs[1] + Bf, gg = acs[2] + Bg, go = acs[3] + Bo;
      c = fsig(gf) * c + fsig(gi) * ftanh(gg);
      float h = fsig(go) * ftanh(c);
      u32 bits = f2b(h);
      u32 other = (u32)__shfl_down((int)bits, 16);   // pairs even/odd lhi (units 2k,2k+1)
      if ((lhi & 1) == 0) {
        u32* dst = hslot(ws, dir, t + 1) + batch * 256 + (unit >> 1);
        astore(dst, bits | (other << 16));
      }
    }
    // [G] prefetch next emb IN THE SHADOW (after h-store issued)
    if (t != T - 1) stage_emb(t + 1);
    __syncthreads();   // [I] emb staged for next [B]; h reads done before next [D]
  }

  // ---- tail E1: h_enc = [hf|hb] @ enc_hW^T + enc_hb ----
  {
    u32* wlu = reinterpret_cast<u32*>(&Wl[0][0]);   // reuse as hcat[b][1024] bf16
    const u32* hf = hslot(ws, 0, T);
    const u32* hb = hslot(ws, 1, T);
    u32 tmp[32];
    #pragma unroll
    for (int j = 0; j < 32; ++j) {
      int i = tid + j * 512, b = i >> 9, k = i & 511;
      tmp[j] = (k < 256) ? aload(hf + b * 256 + k) : aload(hb + b * 256 + (k - 256));
    }
    int guard = 0;
    while (true) {
      bool bad = false;
      #pragma unroll
      for (int j = 0; j < 32; ++j)
        if (tmp[j] == POISON) {
          bad = true;
          int i = tid + j * 512, b = i >> 9, k = i & 511;
          tmp[j] = (k < 256) ? aload(hf + b * 256 + k) : aload(hb + b * 256 + (k - 256));
        }
      if (!bad || ++guard > GUARD) break;
      __builtin_amdgcn_s_sleep(1);
    }
    #pragma unroll
    for (int j = 0; j < 32; ++j) wlu[tid + j * 512] = tmp[j];
  }
  __syncthreads();
  if (tid < 256) {
    const u16* hcat = &Wl[0][0];
    int b = tid >> 3, jc = tid & 7;
    int j = wg * 8 + jc;
    float s = enc_hb[j];
    const float4* w4 = reinterpret_cast<const float4*>(enc_hW + (size_t)j * 1024);
    for (int kk = 0; kk < 256; ++kk) {
      float4 wv4 = w4[kk];
      const u16* hp = hcat + b * 1024 + kk * 4;
      s += wv4.x * b2f(hp[0]) + wv4.y * b2f(hp[1]) + wv4.z * b2f(hp[2]) + wv4.w * b2f(hp[3]);
    }
    u32 bits = f2b(s);
    u32 other = (u32)__shfl_down((int)bits, 1);
    if ((jc & 1) == 0) {
      u32* dst = reinterpret_cast<u32*>(ws + OFF_HENC) + b * 256 + j / 2;
      astore(dst, bits | (other << 16));
    }
  }
  __syncthreads();

  // ---- tail E2: mu/sigma/z/kl (scratch = act) ----
  {
    u32* hhu = reinterpret_cast<u32*>(&act[0][0]);  // tight [b][512] bf16
    const u32* he = reinterpret_cast<const u32*>(ws + OFF_HENC);
    u32 tmp[16];
    #pragma unroll
    for (int j = 0; j < 16; ++j) tmp[j] = aload(he + tid + j * 512);
    int guard = 0;
    while (true) {
      bool bad = false;
      #pragma unroll
      for (int j = 0; j < 16; ++j)
        if (tmp[j] == POISON) { bad = true; tmp[j] = aload(he + tid + j * 512); }
      if (!bad || ++guard > GUARD) break;
      __builtin_amdgcn_s_sleep(1);
    }
    #pragma unroll
    for (int j = 0; j < 16; ++j) hhu[tid + j * 512] = tmp[j];
  }
  __syncthreads();
  {
    const u16* hh = &act[0][0];
    int b = tid >> 4, l16 = tid & 15;
    float pm = 0.f, ps = 0.f;
    const float* mwr = mu_W + (size_t)wg * H;
    const float* swr = std_W + (size_t)wg * H;
    for (int k = l16 * 32; k < l16 * 32 + 32; ++k) {
      float hv = b2f(hh[b * H + k]);
      pm += mwr[k] * hv;
      ps += swr[k] * hv;
    }
    gates[b][l16] = pm;
    gates[32 + b][l16] = ps;
  }
  __syncthreads();
  if (tid < 32) {
    int b = tid;
    float mu = mu_b[wg], sv = std_b[wg];
    for (int l = 0; l < 16; ++l) { mu += gates[b][l]; sv += gates[32 + b][l]; }
    float sig = fmaxf(sv, 0.f) + log1pf(__expf(-fabsf(sv)));
    float zv = mu + sig * epsv[wg];
    reinterpret_cast<float*>(ws + OFF_Z)[b * Z + wg] = zv;
    gates[b][16] = -0.5f * (1.f + logf(sig) - mu * mu - sig);
  }
  __syncthreads();
  if (tid == 0) {
    float kl = 0.f;
    for (int b = 0; b < 32; ++b) kl += gates[b][16];
    reinterpret_cast<float*>(ws + OFF_KLP)[wg] = kl;
  }
}

// ===================================================================
// PHASE B (persistent, 224 WGs <= 256 CUs -> all co-resident):
//   bid 0..31   : decoder LSTM
//   bid 32..156 : GEMM worker w=bid-32 (<125): fixed ct=w, rt 0..31 ascending
//                 -> Bt stays L2-resident, order tracks decoder production
//   bid 157..223: ly workers (concurrent with GEMM)
//   f1: workers 0..7 after GEMM; f2: worker 0
// All cross-WG producer stores are AGENT-SCOPE ATOMICS.
// ===================================================================
__global__ __launch_bounds__(512, 1) void phaseB_k(
    const int* __restrict__ x, const int* __restrict__ y,
    const float* __restrict__ emb,
    const float* __restrict__ Wih, const float* __restrict__ Whh, const float* __restrict__ bv,
    const float* __restrict__ dec_hW, const float* __restrict__ dec_hb,
    const float* __restrict__ out_W, const float* __restrict__ out_b,
    char* __restrict__ ws, float* __restrict__ out)
{
  __shared__ __align__(16) char smem[157440];
  const int tid = threadIdx.x;
  const int bid = blockIdx.x;
  u32* hsu = reinterpret_cast<u32*>(ws + OFF_HS);          // t-major: row r=(t*B+b), 256 u32
  const int wid = tid >> 6, lane = tid & 63, l15 = lane & 15, lhi = lane >> 4;

  if (bid < 32) {
    // ================= decoder LSTM =================
    u16 (*Wl)[776]  = reinterpret_cast<u16(*)[776]>(smem);
    u16 (*act)[776] = reinterpret_cast<u16(*)[776]>(smem + 99328);
    const int wg = bid;
    const int u0 = wg * 16;

    {
      int r = tid >> 3, s8 = tid & 7;
      int grow = (r & 3) * H + u0 + (r >> 2);   // gate-interleaved
      for (int kc = s8 * 96; kc < s8 * 96 + 96; kc += 8) {
        const float4* p;
        if (kc < E) p = reinterpret_cast<const float4*>(Wih + (size_t)grow * E + kc);
        else        p = reinterpret_cast<const float4*>(Whh + (size_t)grow * H + (kc - E));
        float4 a = p[0], b4 = p[1];
        Wl[r][kc+0] = f2b(a.x);  Wl[r][kc+1] = f2b(a.y);  Wl[r][kc+2] = f2b(a.z);  Wl[r][kc+3] = f2b(a.w);
        Wl[r][kc+4] = f2b(b4.x); Wl[r][kc+5] = f2b(b4.y); Wl[r][kc+6] = f2b(b4.z); Wl[r][kc+7] = f2b(b4.w);
      }
    }

    const int ab = tid >> 4, au = tid & 15;
    const int mq = wid & 3, nh = wid >> 2;
    const int unit = u0 + mq * 4 + lhi;
    const int batch = nh * 16 + l15;
    const float Bi = bv[0*H + unit], Bf = bv[1*H + unit];
    const float Bg = bv[2*H + unit], Bo = bv[3*H + unit];
    float c = 0.f;

    u32* h0u = reinterpret_cast<u32*>(ws + OFF_H0);
    const float* zws = reinterpret_cast<const float*>(ws + OFF_Z);
    u32* actu = reinterpret_cast<u32*>(&act[0][0]);

    auto stage_emb = [&](int t) {
      const float* src = emb + (size_t)x[ab * T + t] * E + au * 16;
      const float4* s4 = reinterpret_cast<const float4*>(src);
      float4 A0 = s4[0], A1 = s4[1], A2 = s4[2], A3 = s4[3];
      u32 w0 = f2b(A0.x) | ((u32)f2b(A0.y) << 16);
      u32 w1 = f2b(A0.z) | ((u32)f2b(A0.w) << 16);
      u32 w2 = f2b(A1.x) | ((u32)f2b(A1.y) << 16);
      u32 w3 = f2b(A1.z) | ((u32)f2b(A1.w) << 16);
      u32 w4 = f2b(A2.x) | ((u32)f2b(A2.y) << 16);
      u32 w5 = f2b(A2.z) | ((u32)f2b(A2.w) << 16);
      u32 w6 = f2b(A3.x) | ((u32)f2b(A3.y) << 16);
      u32 w7 = f2b(A3.z) | ((u32)f2b(A3.w) << 16);
      u32* dst = actu + ab * 388 + au * 8;
      reinterpret_cast<uint4*>(dst)[0] = make_uint4(w0, w1, w2, w3);
      reinterpret_cast<uint4*>(dst)[1] = make_uint4(w4, w5, w6, w7);
    };

    stage_emb(0);

    // phase 0: h0 = tanh(z @ dec_hW^T + dec_hb)
    {
      float s = dec_hb[u0 + au];
      const float* wr = dec_hW + (size_t)(u0 + au) * Z;
      for (int zz = 0; zz < Z; ++zz) s += wr[zz] * zws[ab * Z + zz];
      float h0 = ftanh(s);
      u32 bits = f2b(h0);
      u32 other = (u32)__shfl_down((int)bits, 1);
      if ((au & 1) == 0) astore(h0u + ab * 256 + (u0 + au) / 2, bits | (other << 16));
    }
    __syncthreads();

    const u16* wrow = &Wl[mq * 16 + l15][0];
    const u16* arow = &act[nh * 16 + l15][0];

    for (int t = 0; t < T; ++t) {
      f32x4 ac[4];
      #pragma unroll
      for (int i = 0; i < 4; ++i) ac[i] = {0, 0, 0, 0};

      // [A] issue coalesced h loads
      const u32* base = (t == 0) ? h0u : (hsu + (size_t)(t - 1) * B * 256);
      u32 tmp[16];
      #pragma unroll
      for (int j = 0; j < 16; ++j) tmp[j] = aload(base + tid + j * 512);

      // [B] emb-part MFMA under load/poll latency
      #pragma unroll
      for (int fe = 0; fe < 8; ++fe) {
        int kk = fe * 32 + lhi * 8;
        s16x8 A = *reinterpret_cast<const s16x8*>(wrow + kk);
        s16x8 Bv = *reinterpret_cast<const s16x8*>(arow + kk);
        ac[fe & 3] = __builtin_amdgcn_mfma_f32_16x16x32_bf16(A, Bv, ac[fe & 3], 0, 0, 0);
      }

      // [C] poll
      {
        int guard = 0;
        while (true) {
          bool bad = false;
          #pragma unroll
          for (int j = 0; j < 16; ++j)
            if (tmp[j] == POISON) { bad = true; tmp[j] = aload(base + tid + j * 512); }
          if (!bad || ++guard > GUARD) break;
          __builtin_amdgcn_s_sleep(1);
        }
      }
      // [D] h -> LDS
      #pragma unroll
      for (int j = 0; j < 16; ++j) {
        int i = tid + j * 512;
        actu[(i >> 8) * 388 + 128 + (i & 255)] = tmp[j];
      }
      __syncthreads();   // [E]

      // [F] h-part MFMA + nonlinearity + h store
      {
        #pragma unroll
        for (int f = 0; f < 16; ++f) {
          int kk = 256 + f * 32 + lhi * 8;
          s16x8 A = *reinterpret_cast<const s16x8*>(wrow + kk);
          s16x8 Bv = *reinterpret_cast<const s16x8*>(arow + kk);
          ac[f & 3] = __builtin_amdgcn_mfma_f32_16x16x32_bf16(A, Bv, ac[f & 3], 0, 0, 0);
        }
        f32x4 acs = (ac[0] + ac[1]) + (ac[2] + ac[3]);
        float gi = acs[0] + Bi, gf = acs[1] + Bf, gg = acs[2] + Bg, go = acs[3] + Bo;
        c = fsig(gf) * c + fsig(gi) * ftanh(gg);
        float h = fsig(go) * ftanh(c);
        u32 bits = f2b(h);
        u32 other = (u32)__shfl_down((int)bits, 16);
        if ((lhi & 1) == 0) {
          u32* dst = hsu + (size_t)(t * B + batch) * 256 + (unit >> 1);   // t-major
          astore(dst, bits | (other << 16));
        }
      }
      // [G] prefetch next emb in the shadow (after h-store)
      if (t != T - 1) stage_emb(t + 1);
      __syncthreads();   // [I]
    }
    return;
  }

  // ================= persistent worker =================
  const int w = bid - 32;     // 0..191
  u16 (*At)[72] = reinterpret_cast<u16(*)[72]>(smem);            // 128 x 72
  u16 (*Bt)[72] = reinterpret_cast<u16(*)[72]>(smem + 18432);    // 256 x 72
  float* red = reinterpret_cast<float*>(smem + 55296);           // [2][64][4][2]
  const u16* Wb = reinterpret_cast<const u16*>(ws + OFF_WB);
  const int wm = wid & 1, wn = wid >> 1;
  const int sr = tid >> 3, ss = tid & 7;

  if (w < 125) {
    // ---- GEMM + per-chunk logsumexp: fixed ct=w, rt ascending ----
    const int col0 = w * 256;
    for (int rt = 0; rt < 32; ++rt) {
      const int row0 = rt * 128;

      f32x4 acc[4][4];
      #pragma unroll
      for (int i = 0; i < 4; ++i)
        #pragma unroll
        for (int j = 0; j < 4; ++j) acc[i][j] = {0, 0, 0, 0};

      for (int kt = 0; kt < 8; ++kt) {
        // stage At (hs rows, poll for validity)
        #pragma unroll
        for (int it = 0; it < 2; ++it) {
          int r = it * 64 + sr;
          const u32* p = hsu + (size_t)(row0 + r) * 256 + kt * 32 + ss * 4;
          u32 a0 = aload(p), a1 = aload(p + 1), a2 = aload(p + 2), a3 = aload(p + 3);
          int guard = 0;
          while ((a0 == POISON || a1 == POISON || a2 == POISON || a3 == POISON) && ++guard <= GUARD) {
            __builtin_amdgcn_s_sleep(64);
            a0 = aload(p); a1 = aload(p + 1); a2 = aload(p + 2); a3 = aload(p + 3);
          }
          u32* d = reinterpret_cast<u32*>(&At[r][ss * 8]);
          d[0] = a0; d[1] = a1; d[2] = a2; d[3] = a3;
        }
        // stage Bt (weights; L2-resident after rt=0)
        #pragma unroll
        for (int it = 0; it < 4; ++it) {
          int r = it * 64 + sr;
          *reinterpret_cast<s16x8*>(&Bt[r][ss * 8]) =
              *reinterpret_cast<const s16x8*>(Wb + (size_t)(col0 + r) * H + kt * 64 + ss * 8);
        }
        __syncthreads();
        #pragma unroll
        for (int ks = 0; ks < 2; ++ks) {
          int kk = ks * 32 + lhi * 8;
          s16x8 af[4], bf[4];
          #pragma unroll
          for (int mi = 0; mi < 4; ++mi)
            af[mi] = *reinterpret_cast<const s16x8*>(&At[wm * 64 + mi * 16 + l15][kk]);
          #pragma unroll
          for (int ni = 0; ni < 4; ++ni)
            bf[ni] = *reinterpret_cast<const s16x8*>(&Bt[wn * 64 + ni * 16 + l15][kk]);
          #pragma unroll
          for (int mi = 0; mi < 4; ++mi)
            #pragma unroll
            for (int ni = 0; ni < 4; ++ni)
              acc[mi][ni] = __builtin_amdgcn_mfma_f32_16x16x32_bf16(af[mi], bf[ni], acc[mi][ni], 0, 0, 0);
        }
        __syncthreads();
      }

      float bias[4];
      #pragma unroll
      for (int ni = 0; ni < 4; ++ni) bias[ni] = out_b[col0 + wn * 64 + ni * 16 + l15];

      #pragma unroll
      for (int mi = 0; mi < 4; ++mi) {
        #pragma unroll
        for (int reg = 0; reg < 4; ++reg) {
          float l0 = acc[mi][0][reg] + bias[0];
          float l1 = acc[mi][1][reg] + bias[1];
          float l2 = acc[mi][2][reg] + bias[2];
          float l3 = acc[mi][3][reg] + bias[3];
          float m = fmaxf(fmaxf(l0, l1), fmaxf(l2, l3));
          for (int d = 1; d < 16; d <<= 1) m = fmaxf(m, __shfl_xor(m, d, 16));
          float s = __expf(l0 - m) + __expf(l1 - m) + __expf(l2 - m) + __expf(l3 - m);
          for (int d = 1; d < 16; d <<= 1) s += __shfl_xor(s, d, 16);
          if (l15 == 0) {
            int lr = mi * 16 + lhi * 4 + reg;
            red[((wm * 64 + lr) * 4 + wn) * 2 + 0] = m;
            red[((wm * 64 + lr) * 4 + wn) * 2 + 1] = s;
          }
        }
      }
      __syncthreads();
      if (tid < 128) {
        int lr = tid;
        float M = -3.0e38f, S = 0.f;
        #pragma unroll
        for (int wnn = 0; wnn < 4; ++wnn) {
          float m = red[(lr * 4 + wnn) * 2 + 0];
          float s = red[(lr * 4 + wnn) * 2 + 1];
          float nm = fmaxf(M, m);
          S = S * __expf(M - nm) + s * __expf(m - nm);
          M = nm;
        }
        // CEP [chunk][row]: contiguous 128-row writes (coalesced)
        u32* cepw = reinterpret_cast<u32*>(ws + OFF_CEP);
        size_t ix = ((size_t)w * 4096 + row0 + lr) * 2;
        afstore(cepw + ix + 0, M);
        afstore(cepw + ix + 1, S);
      }
      __syncthreads();
    }
  } else {
    // ---- ly: exact logit at target (workers 125..191, one wave per row) ----
    for (int r = (w - 125) * 8 + wid; r < 4096; r += 67 * 8) {
      int t = r >> 5, b = r & 31;
      int yy = y[b * T + t];
      const u32* hp = hsu + (size_t)r * 256 + lane * 4;
      u32 a0 = aload(hp), a1 = aload(hp + 1), a2 = aload(hp + 2), a3 = aload(hp + 3);
      int guard = 0;
      while ((a0 == POISON || a1 == POISON || a2 == POISON || a3 == POISON) && ++guard <= GUARD) {
        __builtin_amdgcn_s_sleep(64);
        a0 = aload(hp); a1 = aload(hp + 1); a2 = aload(hp + 2); a3 = aload(hp + 3);
      }
      const float4* wp = reinterpret_cast<const float4*>(out_W + (size_t)yy * H + lane * 8);
      float4 w0 = wp[0], w1 = wp[1];
      float s = b2f((u16)(a0 & 0xFFFF)) * w0.x + b2f((u16)(a0 >> 16)) * w0.y
              + b2f((u16)(a1 & 0xFFFF)) * w0.z + b2f((u16)(a1 >> 16)) * w0.w
              + b2f((u16)(a2 & 0xFFFF)) * w1.x + b2f((u16)(a2 >> 16)) * w1.y
              + b2f((u16)(a3 & 0xFFFF)) * w1.z + b2f((u16)(a3 >> 16)) * w1.w;
      for (int d = 1; d < 64; d <<= 1) s += __shfl_xor(s, d);
      if (lane == 0)
        afstore(reinterpret_cast<u32*>(ws + OFF_LGY) + r, s + out_b[yy]);
    }
  }

  // ---- f1: combine chunks -> per-row CE (workers 0..7, one row/thread) ----
  {
    int r = w * 512 + tid;
    if (r < 4096) {
      const u32* lgyu = reinterpret_cast<const u32*>(ws + OFF_LGY);
      u32 lb = aload(lgyu + r);
      int guard = 0;
      while (lb == POISON && ++guard <= GUARD) { __builtin_amdgcn_s_sleep(64); lb = aload(lgyu + r); }
      float ly = __builtin_bit_cast(float, lb);
      const u32* cp = reinterpret_cast<const u32*>(ws + OFF_CEP);
      float M = -3.0e38f, S = 0.f;
      for (int cch = 0; cch < 125; ++cch) {
        size_t ix = ((size_t)cch * 4096 + r) * 2;
        u32 ma = aload(cp + ix), sa = aload(cp + ix + 1);
        int g2 = 0;
        while ((ma == POISON || sa == POISON) && ++g2 <= GUARD) {
          __builtin_amdgcn_s_sleep(64);
          ma = aload(cp + ix); sa = aload(cp + ix + 1);
        }
        float m = __builtin_bit_cast(float, ma), s = __builtin_bit_cast(float, sa);
        float nm = fmaxf(M, m);
        S = S * __expf(M - nm) + s * __expf(m - nm);
        M = nm;
      }
      afstore(reinterpret_cast<u32*>(ws + OFF_CER) + r, M + logf(S) - ly);
    }
  }

  // ---- f2: final reduction (worker 0 only) ----
  if (w == 0) {
    __syncthreads();
    float* rb = reinterpret_cast<float*>(smem);
    const u32* ceru = reinterpret_cast<const u32*>(ws + OFF_CER);
    const float* klp = reinterpret_cast<const float*>(ws + OFF_KLP);
    float s = 0.f;
    for (int j = 0; j < 8; ++j) {
      int r = tid + j * 512;
      u32 v = aload(ceru + r);
      int guard = 0;
      while (v == POISON && ++guard <= GUARD) { __builtin_amdgcn_s_sleep(64); v = aload(ceru + r); }
      s += __builtin_bit_cast(float, v);
    }
    if (tid < 64) s += klp[tid];
    rb[tid] = s;
    __syncthreads();
    for (int d = 256; d > 0; d >>= 1) {
      if (tid < d) rb[tid] += rb[tid + d];
      __syncthreads();
    }
    if (tid == 0) out[0] = rb[0] / 32.f;
  }
}

extern "C" void kernel_launch(void* const* d_in, const int* in_sizes, int n_in,
                              void* d_out, int out_size, void* d_ws, size_t ws_size,
                              hipStream_t stream) {
  (void)in_sizes; (void)n_in; (void)out_size; (void)ws_size;
  const int*   x       = (const int*)d_in[0];
  const int*   y       = (const int*)d_in[1];
  const float* epsv    = (const float*)d_in[2];
  const float* enc_emb = (const float*)d_in[3];
  const float* dec_emb = (const float*)d_in[4];
  const float* fWih    = (const float*)d_in[5];
  const float* fWhh    = (const float*)d_in[6];
  const float* fb      = (const float*)d_in[7];
  const float* bWih    = (const float*)d_in[8];
  const float* bWhh    = (const float*)d_in[9];
  const float* bb      = (const float*)d_in[10];
  const float* dWih    = (const float*)d_in[11];
  const float* dWhh    = (const float*)d_in[12];
  const float* db      = (const float*)d_in[13];
  const float* enc_hW  = (const float*)d_in[14];
  const float* enc_hb  = (const float*)d_in[15];
  const float* mu_W    = (const float*)d_in[16];
  const float* mu_b    = (const float*)d_in[17];
  const float* std_W   = (const float*)d_in[18];
  const float* std_b   = (const float*)d_in[19];
  const float* dec_hW  = (const float*)d_in[20];
  const float* dec_hb  = (const float*)d_in[21];
  const float* out_W   = (const float*)d_in[22];
  const float* out_b   = (const float*)d_in[23];
  char* ws = (char*)d_ws;

  // per-launch state: zero initial h slots; poison all dataflow buffers
  hipMemsetAsync(ws + OFF_ZF, 0x00, 65536, stream);
  hipMemsetAsync(ws + OFF_PF, 0xFF, OFF_PEND - OFF_PF, stream);

  phaseA_k<<<192, 512, 0, stream>>>(x, enc_emb, fWih, fWhh, fb, bWih, bWhh, bb,
                                    enc_hW, enc_hb, mu_W, mu_b, std_W, std_b,
                                    epsv, out_W, ws);

  // re-poison the CEP overlay (aliases enc fwd h-slots; stream-ordered after phaseA)
  hipMemsetAsync(ws + OFF_CEP, 0xFF, 4096000, stream);

  phaseB_k<<<224, 512, 0, stream>>>(x, y, dec_emb, dWih, dWhh, db, dec_hW, dec_hb,
                                    out_W, out_b, ws, (float*)d_out);
}

// Round 15
// 1103.161 us; speedup vs baseline: 1.1922x; 1.1922x over previous
//
#include <hip/hip_runtime.h>
#include <hip/hip_bf16.h>

typedef float f32x4 __attribute__((ext_vector_type(4)));
typedef short s16x8 __attribute__((ext_vector_type(8)));
typedef unsigned int u32;
typedef unsigned short u16;

#define DEV static __device__ __forceinline__

namespace {
constexpr int V = 32000, E = 256, H = 512, Z = 64, B = 32, T = 128;
constexpr u32 POISON = 0xFFFFFFFFu;
constexpr int GUARD = 1 << 20;

// ---- workspace layout (bytes); total extent 45,523,200 ----
constexpr size_t OFF_ZF   = 0;                          // fwd h slot 0 (zeros, 32KB)
constexpr size_t OFF_ZB   = 32768;                      // bwd h slot 0 (zeros, 32KB)
constexpr size_t OFF_PF   = 65536;                      // fwd h slots 1..128 (4MB)
constexpr size_t OFF_PB   = OFF_PF + (size_t)T * 32768; // bwd h slots (4MB); dec ping-pong in phaseB
constexpr size_t OFF_H0   = OFF_PB + (size_t)T * 32768; // dec h0 (32KB)
constexpr size_t OFF_HENC = OFF_H0 + 32768;             // h_enc (32KB)
constexpr size_t OFF_HS   = OFF_HENC + 32768;           // hs, T-MAJOR [t][b][H] bf16 (4MB)
constexpr size_t OFF_LGY  = OFF_HS + (size_t)B*T*H*2;   // 4096 f32
constexpr size_t OFF_CER  = OFF_LGY + 16384;            // 4096 f32
constexpr size_t OFF_PEND = OFF_CER + 16384;            // poison end
constexpr size_t OFF_Z    = OFF_PEND;                   // B*Z f32 (not poisoned)
constexpr size_t OFF_KLP  = OFF_Z + 8192;               // Z f32 (not poisoned)
constexpr size_t OFF_WB   = OFF_KLP + 256;              // V*H bf16 = 32,768,000
constexpr size_t OFF_CEP  = OFF_PF;                     // OVERLAY on enc fwd h-slots (dead in phaseB)
// CEP layout: [chunk ct][row r] float2 -> contiguous 128-row writes
}

DEV u16 f2b(float f) {
  u32 x = __builtin_bit_cast(u32, f);
  return (u16)((x + 0x7fffu + ((x >> 16) & 1u)) >> 16);
}
DEV float b2f(u16 u) {
  u32 x = ((u32)u) << 16;
  return __builtin_bit_cast(float, x);
}
DEV float fsig(float x) { return 1.f / (1.f + __expf(-x)); }
DEV float ftanh(float x) { return 2.f / (1.f + __expf(-2.f * x)) - 1.f; }

DEV u32 aload(const u32* p) { return __hip_atomic_load(p, __ATOMIC_RELAXED, __HIP_MEMORY_SCOPE_AGENT); }
DEV void astore(u32* p, u32 v) { __hip_atomic_store(p, v, __ATOMIC_RELAXED, __HIP_MEMORY_SCOPE_AGENT); }
DEV void afstore(u32* p, float v) { astore(p, __builtin_bit_cast(u32, v)); }

DEV u32* hslot(char* ws, int dir, int s) {
  size_t off = (s == 0) ? (dir ? OFF_ZB : OFF_ZF)
                        : ((dir ? OFF_PB : OFF_PF) + (size_t)(s - 1) * 32768);
  return reinterpret_cast<u32*>(ws + off);
}

// ===================================================================
// PHASE A: encoder (64 WGs) + out_W cast (128 WGs)   [192 WGs total]
// ===================================================================
__global__ __launch_bounds__(512, 1) void phaseA_k(
    const int* __restrict__ x, const float* __restrict__ emb,
    const float* __restrict__ fWih, const float* __restrict__ fWhh, const float* __restrict__ fb,
    const float* __restrict__ bWih, const float* __restrict__ bWhh, const float* __restrict__ bb,
    const float* __restrict__ enc_hW, const float* __restrict__ enc_hb,
    const float* __restrict__ mu_W, const float* __restrict__ mu_b,
    const float* __restrict__ std_W, const float* __restrict__ std_b,
    const float* __restrict__ epsv, const float* __restrict__ out_W,
    char* __restrict__ ws)
{
  __shared__ __align__(16) u16 Wl[64][776];      // weights (gate-interleaved rows)
  __shared__ __align__(16) u16 act[32][776];     // [b][emb(256) | h(512)]
  __shared__ __align__(16) float gates[64][33];  // tails only

  const int tid = threadIdx.x;
  const int wg = blockIdx.x;

  if (wg >= 64) {
    // ---------------- cast out_W -> bf16 (grid-stride, 128 WGs) ----------------
    const size_t total = (size_t)V * H / 8;   // 2,048,000
    for (size_t idx = (size_t)(wg - 64) * 512 + tid; idx < total; idx += (size_t)128 * 512) {
      const float4* src = reinterpret_cast<const float4*>(out_W + idx * 8);
      float4 a = src[0], b = src[1];
      s16x8 o;
      o[0] = (short)f2b(a.x); o[1] = (short)f2b(a.y); o[2] = (short)f2b(a.z); o[3] = (short)f2b(a.w);
      o[4] = (short)f2b(b.x); o[5] = (short)f2b(b.y); o[6] = (short)f2b(b.z); o[7] = (short)f2b(b.w);
      *reinterpret_cast<s16x8*>(ws + OFF_WB + idx * 16) = o;
    }
    return;
  }

  // ---------------- encoder LSTM ----------------
  const bool bwd = wg >= 32;
  const int dir = bwd ? 1 : 0;
  const int lw = wg & 31;
  const int u0 = lw * 16;
  const float* Wih = bwd ? bWih : fWih;
  const float* Whh = bwd ? bWhh : fWhh;
  const float* bv  = bwd ? bb : fb;

  // weights into LDS, GATE-INTERLEAVED rows: local row r -> unit (r>>2), gate (r&3)
  {
    int r = tid >> 3, s8 = tid & 7;
    int grow = (r & 3) * H + u0 + (r >> 2);
    for (int kc = s8 * 96; kc < s8 * 96 + 96; kc += 8) {
      const float4* p;
      if (kc < E) p = reinterpret_cast<const float4*>(Wih + (size_t)grow * E + kc);
      else        p = reinterpret_cast<const float4*>(Whh + (size_t)grow * H + (kc - E));
      float4 a = p[0], b4 = p[1];
      Wl[r][kc+0] = f2b(a.x);  Wl[r][kc+1] = f2b(a.y);  Wl[r][kc+2] = f2b(a.z);  Wl[r][kc+3] = f2b(a.w);
      Wl[r][kc+4] = f2b(b4.x); Wl[r][kc+5] = f2b(b4.y); Wl[r][kc+6] = f2b(b4.z); Wl[r][kc+7] = f2b(b4.w);
    }
  }

  const int ab = tid >> 4, au = tid & 15;   // emb-staging mapping
  const int wv = tid >> 6, lane = tid & 63, l15 = lane & 15, lhi = lane >> 4;
  const int mq = wv & 3, nh = wv >> 2;
  const int unit = u0 + mq * 4 + lhi;       // this thread's LSTM unit
  const int batch = nh * 16 + l15;          // this thread's batch
  const float Bi = bv[0*H + unit], Bf = bv[1*H + unit];
  const float Bg = bv[2*H + unit], Bo = bv[3*H + unit];
  float c = 0.f;
  u32* actu = reinterpret_cast<u32*>(&act[0][0]);

  auto stage_emb = [&](int t) {
    int tt = bwd ? (T - 1 - t) : t;
    const float* src = emb + (size_t)x[ab * T + tt] * E + au * 16;
    const float4* s4 = reinterpret_cast<const float4*>(src);
    float4 A0 = s4[0], A1 = s4[1], A2 = s4[2], A3 = s4[3];
    u32 w0 = f2b(A0.x) | ((u32)f2b(A0.y) << 16);
    u32 w1 = f2b(A0.z) | ((u32)f2b(A0.w) << 16);
    u32 w2 = f2b(A1.x) | ((u32)f2b(A1.y) << 16);
    u32 w3 = f2b(A1.z) | ((u32)f2b(A1.w) << 16);
    u32 w4 = f2b(A2.x) | ((u32)f2b(A2.y) << 16);
    u32 w5 = f2b(A2.z) | ((u32)f2b(A2.w) << 16);
    u32 w6 = f2b(A3.x) | ((u32)f2b(A3.y) << 16);
    u32 w7 = f2b(A3.z) | ((u32)f2b(A3.w) << 16);
    u32* dst = actu + ab * 388 + au * 8;
    reinterpret_cast<uint4*>(dst)[0] = make_uint4(w0, w1, w2, w3);
    reinterpret_cast<uint4*>(dst)[1] = make_uint4(w4, w5, w6, w7);
  };

  stage_emb(0);
  __syncthreads();

  const u16* wrow = &Wl[mq * 16 + l15][0];
  const u16* arow = &act[nh * 16 + l15][0];

  for (int t = 0; t < T; ++t) {
    f32x4 ac[4];
    #pragma unroll
    for (int i = 0; i < 4; ++i) ac[i] = {0, 0, 0, 0};

    // [A] issue coalesced h(t) loads (lanes consecutive -> 2KB/wave)
    const u32* hsrc = hslot(ws, dir, t);
    u32 tmp[16];
    #pragma unroll
    for (int j = 0; j < 16; ++j) tmp[j] = aload(hsrc + tid + j * 512);

    // [B] emb-part MFMA (K 0..255) under load/poll latency
    #pragma unroll
    for (int fe = 0; fe < 8; ++fe) {
      int kk = fe * 32 + lhi * 8;
      s16x8 A = *reinterpret_cast<const s16x8*>(wrow + kk);
      s16x8 Bv = *reinterpret_cast<const s16x8*>(arow + kk);
      ac[fe & 3] = __builtin_amdgcn_mfma_f32_16x16x32_bf16(A, Bv, ac[fe & 3], 0, 0, 0);
    }

    // [C] poll for data validity
    {
      int guard = 0;
      while (true) {
        bool bad = false;
        #pragma unroll
        for (int j = 0; j < 16; ++j)
          if (tmp[j] == POISON) { bad = true; tmp[j] = aload(hsrc + tid + j * 512); }
        if (!bad || ++guard > GUARD) break;
        __builtin_amdgcn_s_sleep(1);
      }
    }
    // [D] h -> LDS (disjoint from emb region)
    #pragma unroll
    for (int j = 0; j < 16; ++j) {
      int i = tid + j * 512;
      actu[(i >> 8) * 388 + 128 + (i & 255)] = tmp[j];
    }
    __syncthreads();   // [E] h ready; all emb MFMA reads done

    // [F] h-part MFMA (K 256..767) + in-register nonlinearity + h store
    {
      #pragma unroll
      for (int f = 0; f < 16; ++f) {
        int kk = 256 + f * 32 + lhi * 8;
        s16x8 A = *reinterpret_cast<const s16x8*>(wrow + kk);
        s16x8 Bv = *reinterpret_cast<const s16x8*>(arow + kk);
        ac[f & 3] = __builtin_amdgcn_mfma_f32_16x16x32_bf16(A, Bv, ac[f & 3], 0, 0, 0);
      }
      f32x4 acs = (ac[0] + ac[1]) + (ac[2] + ac[3]);
      float gi = acs[0] + Bi, gf = acs[1] + Bf, gg = acs[2] + Bg, go = acs[3] + Bo;
      c = fsig(gf) * c + fsig(gi) * ftanh(gg);
      float h = fsig(go) * ftanh(c);
      u32 bits = f2b(h);
      u32 other = (u32)__shfl_down((int)bits, 16);   // pairs even/odd lhi (units 2k,2k+1)
      if ((lhi & 1) == 0) {
        u32* dst = hslot(ws, dir, t + 1) + batch * 256 + (unit >> 1);
        astore(dst, bits | (other << 16));
      }
    }
    // [G] prefetch next emb IN THE SHADOW (after h-store issued)
    if (t != T - 1) stage_emb(t + 1);
    __syncthreads();   // [I] emb staged for next [B]; h reads done before next [D]
  }

  // ---- tail E1: h_enc = [hf|hb] @ enc_hW^T + enc_hb ----
  {
    u32* wlu = reinterpret_cast<u32*>(&Wl[0][0]);   // reuse as hcat[b][1024] bf16
    const u32* hf = hslot(ws, 0, T);
    const u32* hb = hslot(ws, 1, T);
    u32 tmp[32];
    #pragma unroll
    for (int j = 0; j < 32; ++j) {
      int i = tid + j * 512, b = i >> 9, k = i & 511;
      tmp[j] = (k < 256) ? aload(hf + b * 256 + k) : aload(hb + b * 256 + (k - 256));
    }
    int guard = 0;
    while (true) {
      bool bad = false;
      #pragma unroll
      for (int j = 0; j < 32; ++j)
        if (tmp[j] == POISON) {
          bad = true;
          int i = tid + j * 512, b = i >> 9, k = i & 511;
          tmp[j] = (k < 256) ? aload(hf + b * 256 + k) : aload(hb + b * 256 + (k - 256));
        }
      if (!bad || ++guard > GUARD) break;
      __builtin_amdgcn_s_sleep(1);
    }
    #pragma unroll
    for (int j = 0; j < 32; ++j) wlu[tid + j * 512] = tmp[j];
  }
  __syncthreads();
  if (tid < 256) {
    const u16* hcat = &Wl[0][0];
    int b = tid >> 3, jc = tid & 7;
    int j = wg * 8 + jc;
    float s = enc_hb[j];
    const float4* w4 = reinterpret_cast<const float4*>(enc_hW + (size_t)j * 1024);
    for (int kk = 0; kk < 256; ++kk) {
      float4 wv4 = w4[kk];
      const u16* hp = hcat + b * 1024 + kk * 4;
      s += wv4.x * b2f(hp[0]) + wv4.y * b2f(hp[1]) + wv4.z * b2f(hp[2]) + wv4.w * b2f(hp[3]);
    }
    u32 bits = f2b(s);
    u32 other = (u32)__shfl_down((int)bits, 1);
    if ((jc & 1) == 0) {
      u32* dst = reinterpret_cast<u32*>(ws + OFF_HENC) + b * 256 + j / 2;
      astore(dst, bits | (other << 16));
    }
  }
  __syncthreads();

  // ---- tail E2: mu/sigma/z/kl (scratch = act) ----
  {
    u32* hhu = reinterpret_cast<u32*>(&act[0][0]);  // tight [b][512] bf16
    const u32* he = reinterpret_cast<const u32*>(ws + OFF_HENC);
    u32 tmp[16];
    #pragma unroll
    for (int j = 0; j < 16; ++j) tmp[j] = aload(he + tid + j * 512);
    int guard = 0;
    while (true) {
      bool bad = false;
      #pragma unroll
      for (int j = 0; j < 16; ++j)
        if (tmp[j] == POISON) { bad = true; tmp[j] = aload(he + tid + j * 512); }
      if (!bad || ++guard > GUARD) break;
      __builtin_amdgcn_s_sleep(1);
    }
    #pragma unroll
    for (int j = 0; j < 16; ++j) hhu[tid + j * 512] = tmp[j];
  }
  __syncthreads();
  {
    const u16* hh = &act[0][0];
    int b = tid >> 4, l16 = tid & 15;
    float pm = 0.f, ps = 0.f;
    const float* mwr = mu_W + (size_t)wg * H;
    const float* swr = std_W + (size_t)wg * H;
    for (int k = l16 * 32; k < l16 * 32 + 32; ++k) {
      float hv = b2f(hh[b * H + k]);
      pm += mwr[k] * hv;
      ps += swr[k] * hv;
    }
    gates[b][l16] = pm;
    gates[32 + b][l16] = ps;
  }
  __syncthreads();
  if (tid < 32) {
    int b = tid;
    float mu = mu_b[wg], sv = std_b[wg];
    for (int l = 0; l < 16; ++l) { mu += gates[b][l]; sv += gates[32 + b][l]; }
    float sig = fmaxf(sv, 0.f) + log1pf(__expf(-fabsf(sv)));
    float zv = mu + sig * epsv[wg];
    reinterpret_cast<float*>(ws + OFF_Z)[b * Z + wg] = zv;
    gates[b][16] = -0.5f * (1.f + logf(sig) - mu * mu - sig);
  }
  __syncthreads();
  if (tid == 0) {
    float kl = 0.f;
    for (int b = 0; b < 32; ++b) kl += gates[b][16];
    reinterpret_cast<float*>(ws + OFF_KLP)[wg] = kl;
  }
}

// ===================================================================
// PHASE B (persistent, 224 WGs <= 256 CUs -> all co-resident):
//   bid 0..31  : decoder LSTM (private ping-pong in dead bwd slots +
//                t-major hs for workers)
//   bid 32..223: workers -> GEMM tiles (rt-major grid-stride) -> ly -> f1 -> f2
// All cross-WG producer stores are AGENT-SCOPE ATOMICS.
// ===================================================================
__global__ __launch_bounds__(512, 1) void phaseB_k(
    const int* __restrict__ x, const int* __restrict__ y,
    const float* __restrict__ emb,
    const float* __restrict__ Wih, const float* __restrict__ Whh, const float* __restrict__ bv,
    const float* __restrict__ dec_hW, const float* __restrict__ dec_hb,
    const float* __restrict__ out_W, const float* __restrict__ out_b,
    char* __restrict__ ws, float* __restrict__ out)
{
  __shared__ __align__(16) char smem[157440];
  const int tid = threadIdx.x;
  const int bid = blockIdx.x;
  u32* hsu = reinterpret_cast<u32*>(ws + OFF_HS);          // t-major: row r=(t*B+b), 256 u32
  const int wid = tid >> 6, lane = tid & 63, l15 = lane & 15, lhi = lane >> 4;

  if (bid < 32) {
    // ================= decoder LSTM =================
    u16 (*Wl)[776]  = reinterpret_cast<u16(*)[776]>(smem);
    u16 (*act)[776] = reinterpret_cast<u16(*)[776]>(smem + 99328);
    const int wg = bid;
    const int u0 = wg * 16;

    {
      int r = tid >> 3, s8 = tid & 7;
      int grow = (r & 3) * H + u0 + (r >> 2);   // gate-interleaved
      for (int kc = s8 * 96; kc < s8 * 96 + 96; kc += 8) {
        const float4* p;
        if (kc < E) p = reinterpret_cast<const float4*>(Wih + (size_t)grow * E + kc);
        else        p = reinterpret_cast<const float4*>(Whh + (size_t)grow * H + (kc - E));
        float4 a = p[0], b4 = p[1];
        Wl[r][kc+0] = f2b(a.x);  Wl[r][kc+1] = f2b(a.y);  Wl[r][kc+2] = f2b(a.z);  Wl[r][kc+3] = f2b(a.w);
        Wl[r][kc+4] = f2b(b4.x); Wl[r][kc+5] = f2b(b4.y); Wl[r][kc+6] = f2b(b4.z); Wl[r][kc+7] = f2b(b4.w);
      }
    }

    const int ab = tid >> 4, au = tid & 15;
    const int mq = wid & 3, nh = wid >> 2;
    const int unit = u0 + mq * 4 + lhi;
    const int batch = nh * 16 + l15;
    const float Bi = bv[0*H + unit], Bf = bv[1*H + unit];
    const float Bg = bv[2*H + unit], Bo = bv[3*H + unit];
    float c = 0.f;

    u32* h0u = reinterpret_cast<u32*>(ws + OFF_H0);
    const float* zws = reinterpret_cast<const float*>(ws + OFF_Z);
    u32* actu = reinterpret_cast<u32*>(&act[0][0]);

    auto stage_emb = [&](int t) {
      const float* src = emb + (size_t)x[ab * T + t] * E + au * 16;
      const float4* s4 = reinterpret_cast<const float4*>(src);
      float4 A0 = s4[0], A1 = s4[1], A2 = s4[2], A3 = s4[3];
      u32 w0 = f2b(A0.x) | ((u32)f2b(A0.y) << 16);
      u32 w1 = f2b(A0.z) | ((u32)f2b(A0.w) << 16);
      u32 w2 = f2b(A1.x) | ((u32)f2b(A1.y) << 16);
      u32 w3 = f2b(A1.z) | ((u32)f2b(A1.w) << 16);
      u32 w4 = f2b(A2.x) | ((u32)f2b(A2.y) << 16);
      u32 w5 = f2b(A2.z) | ((u32)f2b(A2.w) << 16);
      u32 w6 = f2b(A3.x) | ((u32)f2b(A3.y) << 16);
      u32 w7 = f2b(A3.z) | ((u32)f2b(A3.w) << 16);
      u32* dst = actu + ab * 388 + au * 8;
      reinterpret_cast<uint4*>(dst)[0] = make_uint4(w0, w1, w2, w3);
      reinterpret_cast<uint4*>(dst)[1] = make_uint4(w4, w5, w6, w7);
    };

    stage_emb(0);

    // phase 0: h0 = tanh(z @ dec_hW^T + dec_hb)
    {
      float s = dec_hb[u0 + au];
      const float* wr = dec_hW + (size_t)(u0 + au) * Z;
      for (int zz = 0; zz < Z; ++zz) s += wr[zz] * zws[ab * Z + zz];
      float h0 = ftanh(s);
      u32 bits = f2b(h0);
      u32 other = (u32)__shfl_down((int)bits, 1);
      if ((au & 1) == 0) astore(h0u + ab * 256 + (u0 + au) / 2, bits | (other << 16));
    }
    __syncthreads();

    const u16* wrow = &Wl[mq * 16 + l15][0];
    const u16* arow = &act[nh * 16 + l15][0];

    for (int t = 0; t < T; ++t) {
      f32x4 ac[4];
      #pragma unroll
      for (int i = 0; i < 4; ++i) ac[i] = {0, 0, 0, 0};

      // [A] issue coalesced h loads from PRIVATE ping-pong (bwd slots, re-poisoned)
      const u32* base = (t == 0) ? h0u
                                 : reinterpret_cast<const u32*>(ws + OFF_PB + (size_t)(t - 1) * 32768);
      u32 tmp[16];
      #pragma unroll
      for (int j = 0; j < 16; ++j) tmp[j] = aload(base + tid + j * 512);

      // [B] emb-part MFMA under load/poll latency
      #pragma unroll
      for (int fe = 0; fe < 8; ++fe) {
        int kk = fe * 32 + lhi * 8;
        s16x8 A = *reinterpret_cast<const s16x8*>(wrow + kk);
        s16x8 Bv = *reinterpret_cast<const s16x8*>(arow + kk);
        ac[fe & 3] = __builtin_amdgcn_mfma_f32_16x16x32_bf16(A, Bv, ac[fe & 3], 0, 0, 0);
      }

      // [C] poll
      {
        int guard = 0;
        while (true) {
          bool bad = false;
          #pragma unroll
          for (int j = 0; j < 16; ++j)
            if (tmp[j] == POISON) { bad = true; tmp[j] = aload(base + tid + j * 512); }
          if (!bad || ++guard > GUARD) break;
          __builtin_amdgcn_s_sleep(1);
        }
      }
      // [D] h -> LDS
      #pragma unroll
      for (int j = 0; j < 16; ++j) {
        int i = tid + j * 512;
        actu[(i >> 8) * 388 + 128 + (i & 255)] = tmp[j];
      }
      __syncthreads();   // [E]

      // [F] h-part MFMA + nonlinearity + dual h store (private + hs for workers)
      {
        #pragma unroll
        for (int f = 0; f < 16; ++f) {
          int kk = 256 + f * 32 + lhi * 8;
          s16x8 A = *reinterpret_cast<const s16x8*>(wrow + kk);
          s16x8 Bv = *reinterpret_cast<const s16x8*>(arow + kk);
          ac[f & 3] = __builtin_amdgcn_mfma_f32_16x16x32_bf16(A, Bv, ac[f & 3], 0, 0, 0);
        }
        f32x4 acs = (ac[0] + ac[1]) + (ac[2] + ac[3]);
        float gi = acs[0] + Bi, gf = acs[1] + Bf, gg = acs[2] + Bg, go = acs[3] + Bo;
        c = fsig(gf) * c + fsig(gi) * ftanh(gg);
        float h = fsig(go) * ftanh(c);
        u32 bits = f2b(h);
        u32 other = (u32)__shfl_down((int)bits, 16);
        if ((lhi & 1) == 0) {
          u32 pack = bits | (other << 16);
          // private recurrence slot (only dec WGs read -> no worker contention)
          u32* dpriv = reinterpret_cast<u32*>(ws + OFF_PB + (size_t)t * 32768) + batch * 256 + (unit >> 1);
          astore(dpriv, pack);
          // t-major hs for GEMM/ly workers (fire-and-forget)
          u32* dhs = hsu + (size_t)(t * B + batch) * 256 + (unit >> 1);
          astore(dhs, pack);
        }
      }
      // [G] prefetch next emb in the shadow (after h-stores)
      if (t != T - 1) stage_emb(t + 1);
      __syncthreads();   // [I]
    }
    return;
  }

  // ================= persistent worker =================
  const int w = bid - 32;     // 0..191
  u16 (*At)[72] = reinterpret_cast<u16(*)[72]>(smem);            // 128 x 72
  u16 (*Bt)[72] = reinterpret_cast<u16(*)[72]>(smem + 18432);    // 256 x 72
  float* red = reinterpret_cast<float*>(smem + 55296);           // [2][64][4][2]
  const u16* Wb = reinterpret_cast<const u16*>(ws + OFF_WB);
  const int wm = wid & 1, wn = wid >> 1;
  const int sr = tid >> 3, ss = tid & 7;

  // ---- GEMM + per-chunk logsumexp, rt-major grid-stride (R12-proven) ----
  for (int tl = w; tl < 4000; tl += 192) {
    const int rt = tl / 125, ct = tl % 125;
    const int row0 = rt * 128, col0 = ct * 256;

    f32x4 acc[4][4];
    #pragma unroll
    for (int i = 0; i < 4; ++i)
      #pragma unroll
      for (int j = 0; j < 4; ++j) acc[i][j] = {0, 0, 0, 0};

    for (int kt = 0; kt < 8; ++kt) {
      // stage At (hs rows, poll for validity)
      #pragma unroll
      for (int it = 0; it < 2; ++it) {
        int r = it * 64 + sr;
        const u32* p = hsu + (size_t)(row0 + r) * 256 + kt * 32 + ss * 4;
        u32 a0 = aload(p), a1 = aload(p + 1), a2 = aload(p + 2), a3 = aload(p + 3);
        int guard = 0;
        while ((a0 == POISON || a1 == POISON || a2 == POISON || a3 == POISON) && ++guard <= GUARD) {
          __builtin_amdgcn_s_sleep(64);
          a0 = aload(p); a1 = aload(p + 1); a2 = aload(p + 2); a3 = aload(p + 3);
        }
        u32* d = reinterpret_cast<u32*>(&At[r][ss * 8]);
        d[0] = a0; d[1] = a1; d[2] = a2; d[3] = a3;
      }
      // stage Bt (weights, no poll)
      #pragma unroll
      for (int it = 0; it < 4; ++it) {
        int r = it * 64 + sr;
        *reinterpret_cast<s16x8*>(&Bt[r][ss * 8]) =
            *reinterpret_cast<const s16x8*>(Wb + (size_t)(col0 + r) * H + kt * 64 + ss * 8);
      }
      __syncthreads();
      #pragma unroll
      for (int ks = 0; ks < 2; ++ks) {
        int kk = ks * 32 + lhi * 8;
        s16x8 af[4], bf[4];
        #pragma unroll
        for (int mi = 0; mi < 4; ++mi)
          af[mi] = *reinterpret_cast<const s16x8*>(&At[wm * 64 + mi * 16 + l15][kk]);
        #pragma unroll
        for (int ni = 0; ni < 4; ++ni)
          bf[ni] = *reinterpret_cast<const s16x8*>(&Bt[wn * 64 + ni * 16 + l15][kk]);
        #pragma unroll
        for (int mi = 0; mi < 4; ++mi)
          #pragma unroll
          for (int ni = 0; ni < 4; ++ni)
            acc[mi][ni] = __builtin_amdgcn_mfma_f32_16x16x32_bf16(af[mi], bf[ni], acc[mi][ni], 0, 0, 0);
      }
      __syncthreads();
    }

    float bias[4];
    #pragma unroll
    for (int ni = 0; ni < 4; ++ni) bias[ni] = out_b[col0 + wn * 64 + ni * 16 + l15];

    #pragma unroll
    for (int mi = 0; mi < 4; ++mi) {
      #pragma unroll
      for (int reg = 0; reg < 4; ++reg) {
        float l0 = acc[mi][0][reg] + bias[0];
        float l1 = acc[mi][1][reg] + bias[1];
        float l2 = acc[mi][2][reg] + bias[2];
        float l3 = acc[mi][3][reg] + bias[3];
        float m = fmaxf(fmaxf(l0, l1), fmaxf(l2, l3));
        for (int d = 1; d < 16; d <<= 1) m = fmaxf(m, __shfl_xor(m, d, 16));
        float s = __expf(l0 - m) + __expf(l1 - m) + __expf(l2 - m) + __expf(l3 - m);
        for (int d = 1; d < 16; d <<= 1) s += __shfl_xor(s, d, 16);
        if (l15 == 0) {
          int lr = mi * 16 + lhi * 4 + reg;
          red[((wm * 64 + lr) * 4 + wn) * 2 + 0] = m;
          red[((wm * 64 + lr) * 4 + wn) * 2 + 1] = s;
        }
      }
    }
    __syncthreads();
    if (tid < 128) {
      int lr = tid;
      float M = -3.0e38f, S = 0.f;
      #pragma unroll
      for (int wnn = 0; wnn < 4; ++wnn) {
        float m = red[(lr * 4 + wnn) * 2 + 0];
        float s = red[(lr * 4 + wnn) * 2 + 1];
        float nm = fmaxf(M, m);
        S = S * __expf(M - nm) + s * __expf(m - nm);
        M = nm;
      }
      // CEP [chunk][row]: contiguous 128-row writes (coalesced)
      u32* cepw = reinterpret_cast<u32*>(ws + OFF_CEP);
      size_t ix = ((size_t)ct * 4096 + row0 + lr) * 2;
      afstore(cepw + ix + 0, M);
      afstore(cepw + ix + 1, S);
    }
    __syncthreads();
  }

  // ---- ly: exact logit at target (one wave per row, grid-stride) ----
  for (int r = w * 8 + wid; r < 4096; r += 192 * 8) {
    int t = r >> 5, b = r & 31;
    int yy = y[b * T + t];
    const u32* hp = hsu + (size_t)r * 256 + lane * 4;
    u32 a0 = aload(hp), a1 = aload(hp + 1), a2 = aload(hp + 2), a3 = aload(hp + 3);
    int guard = 0;
    while ((a0 == POISON || a1 == POISON || a2 == POISON || a3 == POISON) && ++guard <= GUARD) {
      __builtin_amdgcn_s_sleep(64);
      a0 = aload(hp); a1 = aload(hp + 1); a2 = aload(hp + 2); a3 = aload(hp + 3);
    }
    const float4* wp = reinterpret_cast<const float4*>(out_W + (size_t)yy * H + lane * 8);
    float4 w0 = wp[0], w1 = wp[1];
    float s = b2f((u16)(a0 & 0xFFFF)) * w0.x + b2f((u16)(a0 >> 16)) * w0.y
            + b2f((u16)(a1 & 0xFFFF)) * w0.z + b2f((u16)(a1 >> 16)) * w0.w
            + b2f((u16)(a2 & 0xFFFF)) * w1.x + b2f((u16)(a2 >> 16)) * w1.y
            + b2f((u16)(a3 & 0xFFFF)) * w1.z + b2f((u16)(a3 >> 16)) * w1.w;
    for (int d = 1; d < 64; d <<= 1) s += __shfl_xor(s, d);
    if (lane == 0)
      afstore(reinterpret_cast<u32*>(ws + OFF_LGY) + r, s + out_b[yy]);
  }

  // ---- f1: combine chunks -> per-row CE (workers 0..7, one row/thread) ----
  {
    int r = w * 512 + tid;
    if (r < 4096) {
      const u32* lgyu = reinterpret_cast<const u32*>(ws + OFF_LGY);
      u32 lb = aload(lgyu + r);
      int guard = 0;
      while (lb == POISON && ++guard <= GUARD) { __builtin_amdgcn_s_sleep(64); lb = aload(lgyu + r); }
      float ly = __builtin_bit_cast(float, lb);
      const u32* cp = reinterpret_cast<const u32*>(ws + OFF_CEP);
      float M = -3.0e38f, S = 0.f;
      for (int cch = 0; cch < 125; ++cch) {
        size_t ix = ((size_t)cch * 4096 + r) * 2;
        u32 ma = aload(cp + ix), sa = aload(cp + ix + 1);
        int g2 = 0;
        while ((ma == POISON || sa == POISON) && ++g2 <= GUARD) {
          __builtin_amdgcn_s_sleep(64);
          ma = aload(cp + ix); sa = aload(cp + ix + 1);
        }
        float m = __builtin_bit_cast(float, ma), s = __builtin_bit_cast(float, sa);
        float nm = fmaxf(M, m);
        S = S * __expf(M - nm) + s * __expf(m - nm);
        M = nm;
      }
      afstore(reinterpret_cast<u32*>(ws + OFF_CER) + r, M + logf(S) - ly);
    }
  }

  // ---- f2: final reduction (worker 0 only) ----
  if (w == 0) {
    __syncthreads();
    float* rb = reinterpret_cast<float*>(smem);
    const u32* ceru = reinterpret_cast<const u32*>(ws + OFF_CER);
    const float* klp = reinterpret_cast<const float*>(ws + OFF_KLP);
    float s = 0.f;
    for (int j = 0; j < 8; ++j) {
      int r = tid + j * 512;
      u32 v = aload(ceru + r);
      int guard = 0;
      while (v == POISON && ++guard <= GUARD) { __builtin_amdgcn_s_sleep(64); v = aload(ceru + r); }
      s += __builtin_bit_cast(float, v);
    }
    if (tid < 64) s += klp[tid];
    rb[tid] = s;
    __syncthreads();
    for (int d = 256; d > 0; d >>= 1) {
      if (tid < d) rb[tid] += rb[tid + d];
      __syncthreads();
    }
    if (tid == 0) out[0] = rb[0] / 32.f;
  }
}

extern "C" void kernel_launch(void* const* d_in, const int* in_sizes, int n_in,
                              void* d_out, int out_size, void* d_ws, size_t ws_size,
                              hipStream_t stream) {
  (void)in_sizes; (void)n_in; (void)out_size; (void)ws_size;
  const int*   x       = (const int*)d_in[0];
  const int*   y       = (const int*)d_in[1];
  const float* epsv    = (const float*)d_in[2];
  const float* enc_emb = (const float*)d_in[3];
  const float* dec_emb = (const float*)d_in[4];
  const float* fWih    = (const float*)d_in[5];
  const float* fWhh    = (const float*)d_in[6];
  const float* fb      = (const float*)d_in[7];
  const float* bWih    = (const float*)d_in[8];
  const float* bWhh    = (const float*)d_in[9];
  const float* bb      = (const float*)d_in[10];
  const float* dWih    = (const float*)d_in[11];
  const float* dWhh    = (const float*)d_in[12];
  const float* db      = (const float*)d_in[13];
  const float* enc_hW  = (const float*)d_in[14];
  const float* enc_hb  = (const float*)d_in[15];
  const float* mu_W    = (const float*)d_in[16];
  const float* mu_b    = (const float*)d_in[17];
  const float* std_W   = (const float*)d_in[18];
  const float* std_b   = (const float*)d_in[19];
  const float* dec_hW  = (const float*)d_in[20];
  const float* dec_hb  = (const float*)d_in[21];
  const float* out_W   = (const float*)d_in[22];
  const float* out_b   = (const float*)d_in[23];
  char* ws = (char*)d_ws;

  // per-launch state: zero initial h slots; poison all dataflow buffers
  hipMemsetAsync(ws + OFF_ZF, 0x00, 65536, stream);
  hipMemsetAsync(ws + OFF_PF, 0xFF, OFF_PEND - OFF_PF, stream);

  phaseA_k<<<192, 512, 0, stream>>>(x, enc_emb, fWih, fWhh, fb, bWih, bWhh, bb,
                                    enc_hW, enc_hb, mu_W, mu_b, std_W, std_b,
                                    epsv, out_W, ws);

  // re-poison BOTH enc slot arrays (CEP overlay on fwd slots + dec ping-pong
  // in bwd slots); stream-ordered after phaseA, before phaseB
  hipMemsetAsync(ws + OFF_PF, 0xFF, OFF_H0 - OFF_PF, stream);

  phaseB_k<<<224, 512, 0, stream>>>(x, y, dec_emb, dWih, dWhh, db, dec_hW, dec_hb,
                                    out_W, out_b, ws, (float*)d_out);
}

// Round 16
// 1069.990 us; speedup vs baseline: 1.2291x; 1.0310x over previous
//
#include <hip/hip_runtime.h>
#include <hip/hip_bf16.h>

typedef float f32x4 __attribute__((ext_vector_type(4)));
typedef short s16x8 __attribute__((ext_vector_type(8)));
typedef unsigned int u32;
typedef unsigned short u16;

#define DEV static __device__ __forceinline__

namespace {
constexpr int V = 32000, E = 256, H = 512, Z = 64, B = 32, T = 128;
constexpr u32 POISON = 0xFFFFFFFFu;
constexpr int GUARD = 1 << 20;

// ---- workspace layout (bytes); total extent 45,523,200 ----
constexpr size_t OFF_ZF   = 0;                          // fwd h slot 0 (zeros, 32KB)
constexpr size_t OFF_ZB   = 32768;                      // bwd h slot 0 (zeros, 32KB)
constexpr size_t OFF_PF   = 65536;                      // fwd h slots 1..128 (4MB)
constexpr size_t OFF_PB   = OFF_PF + (size_t)T * 32768; // bwd h slots (4MB)
constexpr size_t OFF_H0   = OFF_PB + (size_t)T * 32768; // dec h0 (32KB)
constexpr size_t OFF_HENC = OFF_H0 + 32768;             // h_enc (32KB)
constexpr size_t OFF_HS   = OFF_HENC + 32768;           // hs, T-MAJOR [t][b][H] bf16 (4MB)
constexpr size_t OFF_LGY  = OFF_HS + (size_t)B*T*H*2;   // 4096 f32
constexpr size_t OFF_CER  = OFF_LGY + 16384;            // 4096 f32
constexpr size_t OFF_PEND = OFF_CER + 16384;            // poison end
constexpr size_t OFF_Z    = OFF_PEND;                   // B*Z f32 (not poisoned)
constexpr size_t OFF_KLP  = OFF_Z + 8192;               // Z f32 (not poisoned)
constexpr size_t OFF_WB   = OFF_KLP + 256;              // V*H bf16 = 32,768,000
constexpr size_t OFF_CEP  = OFF_PF;                     // OVERLAY on enc fwd h-slots (dead in phaseB)
// CEP layout (R8-proven): [chunk ct][row r] float2 -> contiguous 128-row writes
}

DEV u16 f2b(float f) {
  u32 x = __builtin_bit_cast(u32, f);
  return (u16)((x + 0x7fffu + ((x >> 16) & 1u)) >> 16);
}
DEV float b2f(u16 u) {
  u32 x = ((u32)u) << 16;
  return __builtin_bit_cast(float, x);
}
DEV float fsig(float x) { return 1.f / (1.f + __expf(-x)); }
DEV float ftanh(float x) { return 2.f / (1.f + __expf(-2.f * x)) - 1.f; }

DEV u32 aload(const u32* p) { return __hip_atomic_load(p, __ATOMIC_RELAXED, __HIP_MEMORY_SCOPE_AGENT); }
DEV void astore(u32* p, u32 v) { __hip_atomic_store(p, v, __ATOMIC_RELAXED, __HIP_MEMORY_SCOPE_AGENT); }
DEV void afstore(u32* p, float v) { astore(p, __builtin_bit_cast(u32, v)); }

DEV u32* hslot(char* ws, int dir, int s) {
  size_t off = (s == 0) ? (dir ? OFF_ZB : OFF_ZF)
                        : ((dir ? OFF_PB : OFF_PF) + (size_t)(s - 1) * 32768);
  return reinterpret_cast<u32*>(ws + off);
}

// ===================================================================
// PHASE A: encoder (64 WGs) + out_W cast (128 WGs)   [192 WGs total]
// ===================================================================
__global__ __launch_bounds__(512, 1) void phaseA_k(
    const int* __restrict__ x, const float* __restrict__ emb,
    const float* __restrict__ fWih, const float* __restrict__ fWhh, const float* __restrict__ fb,
    const float* __restrict__ bWih, const float* __restrict__ bWhh, const float* __restrict__ bb,
    const float* __restrict__ enc_hW, const float* __restrict__ enc_hb,
    const float* __restrict__ mu_W, const float* __restrict__ mu_b,
    const float* __restrict__ std_W, const float* __restrict__ std_b,
    const float* __restrict__ epsv, const float* __restrict__ out_W,
    char* __restrict__ ws)
{
  __shared__ __align__(16) u16 Wl[64][776];      // weights (gate-interleaved rows)
  __shared__ __align__(16) u16 act[32][776];     // [b][emb(256) | h(512)]
  __shared__ __align__(16) float gates[64][33];  // tails only

  const int tid = threadIdx.x;
  const int wg = blockIdx.x;

  if (wg >= 64) {
    // ---------------- cast out_W -> bf16 (grid-stride, 128 WGs) ----------------
    const size_t total = (size_t)V * H / 8;   // 2,048,000
    for (size_t idx = (size_t)(wg - 64) * 512 + tid; idx < total; idx += (size_t)128 * 512) {
      const float4* src = reinterpret_cast<const float4*>(out_W + idx * 8);
      float4 a = src[0], b = src[1];
      s16x8 o;
      o[0] = (short)f2b(a.x); o[1] = (short)f2b(a.y); o[2] = (short)f2b(a.z); o[3] = (short)f2b(a.w);
      o[4] = (short)f2b(b.x); o[5] = (short)f2b(b.y); o[6] = (short)f2b(b.z); o[7] = (short)f2b(b.w);
      *reinterpret_cast<s16x8*>(ws + OFF_WB + idx * 16) = o;
    }
    return;
  }

  // ---------------- encoder LSTM ----------------
  const bool bwd = wg >= 32;
  const int dir = bwd ? 1 : 0;
  const int lw = wg & 31;
  const int u0 = lw * 16;
  const float* Wih = bwd ? bWih : fWih;
  const float* Whh = bwd ? bWhh : fWhh;
  const float* bv  = bwd ? bb : fb;

  // weights into LDS, GATE-INTERLEAVED rows: local row r -> unit (r>>2), gate (r&3)
  {
    int r = tid >> 3, s8 = tid & 7;
    int grow = (r & 3) * H + u0 + (r >> 2);
    for (int kc = s8 * 96; kc < s8 * 96 + 96; kc += 8) {
      const float4* p;
      if (kc < E) p = reinterpret_cast<const float4*>(Wih + (size_t)grow * E + kc);
      else        p = reinterpret_cast<const float4*>(Whh + (size_t)grow * H + (kc - E));
      float4 a = p[0], b4 = p[1];
      Wl[r][kc+0] = f2b(a.x);  Wl[r][kc+1] = f2b(a.y);  Wl[r][kc+2] = f2b(a.z);  Wl[r][kc+3] = f2b(a.w);
      Wl[r][kc+4] = f2b(b4.x); Wl[r][kc+5] = f2b(b4.y); Wl[r][kc+6] = f2b(b4.z); Wl[r][kc+7] = f2b(b4.w);
    }
  }

  const int ab = tid >> 4, au = tid & 15;   // emb-staging mapping
  const int wv = tid >> 6, lane = tid & 63, l15 = lane & 15, lhi = lane >> 4;
  const int mq = wv & 3, nh = wv >> 2;
  const int unit = u0 + mq * 4 + lhi;       // this thread's LSTM unit
  const int batch = nh * 16 + l15;          // this thread's batch
  const float Bi = bv[0*H + unit], Bf = bv[1*H + unit];
  const float Bg = bv[2*H + unit], Bo = bv[3*H + unit];
  float c = 0.f;
  u32* actu = reinterpret_cast<u32*>(&act[0][0]);

  auto stage_emb = [&](int t) {
    int tt = bwd ? (T - 1 - t) : t;
    const float* src = emb + (size_t)x[ab * T + tt] * E + au * 16;
    const float4* s4 = reinterpret_cast<const float4*>(src);
    float4 A0 = s4[0], A1 = s4[1], A2 = s4[2], A3 = s4[3];
    u32 w0 = f2b(A0.x) | ((u32)f2b(A0.y) << 16);
    u32 w1 = f2b(A0.z) | ((u32)f2b(A0.w) << 16);
    u32 w2 = f2b(A1.x) | ((u32)f2b(A1.y) << 16);
    u32 w3 = f2b(A1.z) | ((u32)f2b(A1.w) << 16);
    u32 w4 = f2b(A2.x) | ((u32)f2b(A2.y) << 16);
    u32 w5 = f2b(A2.z) | ((u32)f2b(A2.w) << 16);
    u32 w6 = f2b(A3.x) | ((u32)f2b(A3.y) << 16);
    u32 w7 = f2b(A3.z) | ((u32)f2b(A3.w) << 16);
    u32* dst = actu + ab * 388 + au * 8;
    reinterpret_cast<uint4*>(dst)[0] = make_uint4(w0, w1, w2, w3);
    reinterpret_cast<uint4*>(dst)[1] = make_uint4(w4, w5, w6, w7);
  };

  stage_emb(0);
  __syncthreads();

  const u16* wrow = &Wl[mq * 16 + l15][0];
  const u16* arow = &act[nh * 16 + l15][0];

  for (int t = 0; t < T; ++t) {
    f32x4 ac[4];
    #pragma unroll
    for (int i = 0; i < 4; ++i) ac[i] = {0, 0, 0, 0};

    // [A] issue coalesced h(t) loads (lanes consecutive -> 2KB/wave)
    const u32* hsrc = hslot(ws, dir, t);
    u32 tmp[16];
    #pragma unroll
    for (int j = 0; j < 16; ++j) tmp[j] = aload(hsrc + tid + j * 512);

    // [B] emb-part MFMA (K 0..255) under load/poll latency
    #pragma unroll
    for (int fe = 0; fe < 8; ++fe) {
      int kk = fe * 32 + lhi * 8;
      s16x8 A = *reinterpret_cast<const s16x8*>(wrow + kk);
      s16x8 Bv = *reinterpret_cast<const s16x8*>(arow + kk);
      ac[fe & 3] = __builtin_amdgcn_mfma_f32_16x16x32_bf16(A, Bv, ac[fe & 3], 0, 0, 0);
    }

    // [C] poll for data validity
    {
      int guard = 0;
      while (true) {
        bool bad = false;
        #pragma unroll
        for (int j = 0; j < 16; ++j)
          if (tmp[j] == POISON) { bad = true; tmp[j] = aload(hsrc + tid + j * 512); }
        if (!bad || ++guard > GUARD) break;
        __builtin_amdgcn_s_sleep(1);
      }
    }
    // [D] h -> LDS (disjoint from emb region)
    #pragma unroll
    for (int j = 0; j < 16; ++j) {
      int i = tid + j * 512;
      actu[(i >> 8) * 388 + 128 + (i & 255)] = tmp[j];
    }
    __syncthreads();   // [E] h ready; all emb MFMA reads done

    // [F] h-part MFMA (K 256..767) + in-register nonlinearity + h store
    {
      #pragma unroll
      for (int f = 0; f < 16; ++f) {
        int kk = 256 + f * 32 + lhi * 8;
        s16x8 A = *reinterpret_cast<const s16x8*>(wrow + kk);
        s16x8 Bv = *reinterpret_cast<const s16x8*>(arow + kk);
        ac[f & 3] = __builtin_amdgcn_mfma_f32_16x16x32_bf16(A, Bv, ac[f & 3], 0, 0, 0);
      }
      f32x4 acs = (ac[0] + ac[1]) + (ac[2] + ac[3]);
      float gi = acs[0] + Bi, gf = acs[1] + Bf, gg = acs[2] + Bg, go = acs[3] + Bo;
      c = fsig(gf) * c + fsig(gi) * ftanh(gg);
      float h = fsig(go) * ftanh(c);
      u32 bits = f2b(h);
      u32 other = (u32)__shfl_down((int)bits, 16);   // pairs even/odd lhi (units 2k,2k+1)
      if ((lhi & 1) == 0) {
        u32* dst = hslot(ws, dir, t + 1) + batch * 256 + (unit >> 1);
        astore(dst, bits | (other << 16));
      }
    }
    // [G] prefetch next emb IN THE SHADOW (after h-store issued)
    if (t != T - 1) stage_emb(t + 1);
    __syncthreads();   // [I] emb staged for next [B]; h reads done before next [D]
  }

  // ---- tail E1: h_enc = [hf|hb] @ enc_hW^T + enc_hb ----
  {
    u32* wlu = reinterpret_cast<u32*>(&Wl[0][0]);   // reuse as hcat[b][1024] bf16
    const u32* hf = hslot(ws, 0, T);
    const u32* hb = hslot(ws, 1, T);
    u32 tmp[32];
    #pragma unroll
    for (int j = 0; j < 32; ++j) {
      int i = tid + j * 512, b = i >> 9, k = i & 511;
      tmp[j] = (k < 256) ? aload(hf + b * 256 + k) : aload(hb + b * 256 + (k - 256));
    }
    int guard = 0;
    while (true) {
      bool bad = false;
      #pragma unroll
      for (int j = 0; j < 32; ++j)
        if (tmp[j] == POISON) {
          bad = true;
          int i = tid + j * 512, b = i >> 9, k = i & 511;
          tmp[j] = (k < 256) ? aload(hf + b * 256 + k) : aload(hb + b * 256 + (k - 256));
        }
      if (!bad || ++guard > GUARD) break;
      __builtin_amdgcn_s_sleep(1);
    }
    #pragma unroll
    for (int j = 0; j < 32; ++j) wlu[tid + j * 512] = tmp[j];
  }
  __syncthreads();
  if (tid < 256) {
    const u16* hcat = &Wl[0][0];
    int b = tid >> 3, jc = tid & 7;
    int j = wg * 8 + jc;
    float s = enc_hb[j];
    const float4* w4 = reinterpret_cast<const float4*>(enc_hW + (size_t)j * 1024);
    for (int kk = 0; kk < 256; ++kk) {
      float4 wv4 = w4[kk];
      const u16* hp = hcat + b * 1024 + kk * 4;
      s += wv4.x * b2f(hp[0]) + wv4.y * b2f(hp[1]) + wv4.z * b2f(hp[2]) + wv4.w * b2f(hp[3]);
    }
    u32 bits = f2b(s);
    u32 other = (u32)__shfl_down((int)bits, 1);
    if ((jc & 1) == 0) {
      u32* dst = reinterpret_cast<u32*>(ws + OFF_HENC) + b * 256 + j / 2;
      astore(dst, bits | (other << 16));
    }
  }
  __syncthreads();

  // ---- tail E2: mu/sigma/z/kl (scratch = act) ----
  {
    u32* hhu = reinterpret_cast<u32*>(&act[0][0]);  // tight [b][512] bf16
    const u32* he = reinterpret_cast<const u32*>(ws + OFF_HENC);
    u32 tmp[16];
    #pragma unroll
    for (int j = 0; j < 16; ++j) tmp[j] = aload(he + tid + j * 512);
    int guard = 0;
    while (true) {
      bool bad = false;
      #pragma unroll
      for (int j = 0; j < 16; ++j)
        if (tmp[j] == POISON) { bad = true; tmp[j] = aload(he + tid + j * 512); }
      if (!bad || ++guard > GUARD) break;
      __builtin_amdgcn_s_sleep(1);
    }
    #pragma unroll
    for (int j = 0; j < 16; ++j) hhu[tid + j * 512] = tmp[j];
  }
  __syncthreads();
  {
    const u16* hh = &act[0][0];
    int b = tid >> 4, l16 = tid & 15;
    float pm = 0.f, ps = 0.f;
    const float* mwr = mu_W + (size_t)wg * H;
    const float* swr = std_W + (size_t)wg * H;
    for (int k = l16 * 32; k < l16 * 32 + 32; ++k) {
      float hv = b2f(hh[b * H + k]);
      pm += mwr[k] * hv;
      ps += swr[k] * hv;
    }
    gates[b][l16] = pm;
    gates[32 + b][l16] = ps;
  }
  __syncthreads();
  if (tid < 32) {
    int b = tid;
    float mu = mu_b[wg], sv = std_b[wg];
    for (int l = 0; l < 16; ++l) { mu += gates[b][l]; sv += gates[32 + b][l]; }
    float sig = fmaxf(sv, 0.f) + log1pf(__expf(-fabsf(sv)));
    float zv = mu + sig * epsv[wg];
    reinterpret_cast<float*>(ws + OFF_Z)[b * Z + wg] = zv;
    gates[b][16] = -0.5f * (1.f + logf(sig) - mu * mu - sig);
  }
  __syncthreads();
  if (tid == 0) {
    float kl = 0.f;
    for (int b = 0; b < 32; ++b) kl += gates[b][16];
    reinterpret_cast<float*>(ws + OFF_KLP)[wg] = kl;
  }
}

// ===================================================================
// PHASE B (persistent, 224 WGs <= 256 CUs -> all co-resident):
//   bid 0..31  : decoder LSTM
//   bid 32..223: workers -> GEMM tiles (grid-stride) -> ly -> f1 -> f2
// All cross-WG producer stores are AGENT-SCOPE ATOMICS.
// ===================================================================
__global__ __launch_bounds__(512, 1) void phaseB_k(
    const int* __restrict__ x, const int* __restrict__ y,
    const float* __restrict__ emb,
    const float* __restrict__ Wih, const float* __restrict__ Whh, const float* __restrict__ bv,
    const float* __restrict__ dec_hW, const float* __restrict__ dec_hb,
    const float* __restrict__ out_W, const float* __restrict__ out_b,
    char* __restrict__ ws, float* __restrict__ out)
{
  __shared__ __align__(16) char smem[157440];
  const int tid = threadIdx.x;
  const int bid = blockIdx.x;
  u32* hsu = reinterpret_cast<u32*>(ws + OFF_HS);          // t-major: row r=(t*B+b), 256 u32
  const int wid = tid >> 6, lane = tid & 63, l15 = lane & 15, lhi = lane >> 4;

  if (bid < 32) {
    // ================= decoder LSTM =================
    u16 (*Wl)[776]  = reinterpret_cast<u16(*)[776]>(smem);
    u16 (*act)[776] = reinterpret_cast<u16(*)[776]>(smem + 99328);
    const int wg = bid;
    const int u0 = wg * 16;

    {
      int r = tid >> 3, s8 = tid & 7;
      int grow = (r & 3) * H + u0 + (r >> 2);   // gate-interleaved
      for (int kc = s8 * 96; kc < s8 * 96 + 96; kc += 8) {
        const float4* p;
        if (kc < E) p = reinterpret_cast<const float4*>(Wih + (size_t)grow * E + kc);
        else        p = reinterpret_cast<const float4*>(Whh + (size_t)grow * H + (kc - E));
        float4 a = p[0], b4 = p[1];
        Wl[r][kc+0] = f2b(a.x);  Wl[r][kc+1] = f2b(a.y);  Wl[r][kc+2] = f2b(a.z);  Wl[r][kc+3] = f2b(a.w);
        Wl[r][kc+4] = f2b(b4.x); Wl[r][kc+5] = f2b(b4.y); Wl[r][kc+6] = f2b(b4.z); Wl[r][kc+7] = f2b(b4.w);
      }
    }

    const int ab = tid >> 4, au = tid & 15;
    const int mq = wid & 3, nh = wid >> 2;
    const int unit = u0 + mq * 4 + lhi;
    const int batch = nh * 16 + l15;
    const float Bi = bv[0*H + unit], Bf = bv[1*H + unit];
    const float Bg = bv[2*H + unit], Bo = bv[3*H + unit];
    float c = 0.f;

    u32* h0u = reinterpret_cast<u32*>(ws + OFF_H0);
    const float* zws = reinterpret_cast<const float*>(ws + OFF_Z);
    u32* actu = reinterpret_cast<u32*>(&act[0][0]);

    auto stage_emb = [&](int t) {
      const float* src = emb + (size_t)x[ab * T + t] * E + au * 16;
      const float4* s4 = reinterpret_cast<const float4*>(src);
      float4 A0 = s4[0], A1 = s4[1], A2 = s4[2], A3 = s4[3];
      u32 w0 = f2b(A0.x) | ((u32)f2b(A0.y) << 16);
      u32 w1 = f2b(A0.z) | ((u32)f2b(A0.w) << 16);
      u32 w2 = f2b(A1.x) | ((u32)f2b(A1.y) << 16);
      u32 w3 = f2b(A1.z) | ((u32)f2b(A1.w) << 16);
      u32 w4 = f2b(A2.x) | ((u32)f2b(A2.y) << 16);
      u32 w5 = f2b(A2.z) | ((u32)f2b(A2.w) << 16);
      u32 w6 = f2b(A3.x) | ((u32)f2b(A3.y) << 16);
      u32 w7 = f2b(A3.z) | ((u32)f2b(A3.w) << 16);
      u32* dst = actu + ab * 388 + au * 8;
      reinterpret_cast<uint4*>(dst)[0] = make_uint4(w0, w1, w2, w3);
      reinterpret_cast<uint4*>(dst)[1] = make_uint4(w4, w5, w6, w7);
    };

    stage_emb(0);

    // phase 0: h0 = tanh(z @ dec_hW^T + dec_hb)
    {
      float s = dec_hb[u0 + au];
      const float* wr = dec_hW + (size_t)(u0 + au) * Z;
      for (int zz = 0; zz < Z; ++zz) s += wr[zz] * zws[ab * Z + zz];
      float h0 = ftanh(s);
      u32 bits = f2b(h0);
      u32 other = (u32)__shfl_down((int)bits, 1);
      if ((au & 1) == 0) astore(h0u + ab * 256 + (u0 + au) / 2, bits | (other << 16));
    }
    __syncthreads();

    const u16* wrow = &Wl[mq * 16 + l15][0];
    const u16* arow = &act[nh * 16 + l15][0];

    for (int t = 0; t < T; ++t) {
      f32x4 ac[4];
      #pragma unroll
      for (int i = 0; i < 4; ++i) ac[i] = {0, 0, 0, 0};

      // [A] issue coalesced h loads
      const u32* base = (t == 0) ? h0u : (hsu + (size_t)(t - 1) * B * 256);
      u32 tmp[16];
      #pragma unroll
      for (int j = 0; j < 16; ++j) tmp[j] = aload(base + tid + j * 512);

      // [B] emb-part MFMA under load/poll latency
      #pragma unroll
      for (int fe = 0; fe < 8; ++fe) {
        int kk = fe * 32 + lhi * 8;
        s16x8 A = *reinterpret_cast<const s16x8*>(wrow + kk);
        s16x8 Bv = *reinterpret_cast<const s16x8*>(arow + kk);
        ac[fe & 3] = __builtin_amdgcn_mfma_f32_16x16x32_bf16(A, Bv, ac[fe & 3], 0, 0, 0);
      }

      // [C] poll
      {
        int guard = 0;
        while (true) {
          bool bad = false;
          #pragma unroll
          for (int j = 0; j < 16; ++j)
            if (tmp[j] == POISON) { bad = true; tmp[j] = aload(base + tid + j * 512); }
          if (!bad || ++guard > GUARD) break;
          __builtin_amdgcn_s_sleep(1);
        }
      }
      // [D] h -> LDS
      #pragma unroll
      for (int j = 0; j < 16; ++j) {
        int i = tid + j * 512;
        actu[(i >> 8) * 388 + 128 + (i & 255)] = tmp[j];
      }
      __syncthreads();   // [E]

      // [F] h-part MFMA + nonlinearity + h store
      {
        #pragma unroll
        for (int f = 0; f < 16; ++f) {
          int kk = 256 + f * 32 + lhi * 8;
          s16x8 A = *reinterpret_cast<const s16x8*>(wrow + kk);
          s16x8 Bv = *reinterpret_cast<const s16x8*>(arow + kk);
          ac[f & 3] = __builtin_amdgcn_mfma_f32_16x16x32_bf16(A, Bv, ac[f & 3], 0, 0, 0);
        }
        f32x4 acs = (ac[0] + ac[1]) + (ac[2] + ac[3]);
        float gi = acs[0] + Bi, gf = acs[1] + Bf, gg = acs[2] + Bg, go = acs[3] + Bo;
        c = fsig(gf) * c + fsig(gi) * ftanh(gg);
        float h = fsig(go) * ftanh(c);
        u32 bits = f2b(h);
        u32 other = (u32)__shfl_down((int)bits, 16);
        if ((lhi & 1) == 0) {
          u32* dst = hsu + (size_t)(t * B + batch) * 256 + (unit >> 1);   // t-major
          astore(dst, bits | (other << 16));
        }
      }
      // [G] prefetch next emb in the shadow (after h-store)
      if (t != T - 1) stage_emb(t + 1);
      __syncthreads();   // [I]
    }
    return;
  }

  // ================= persistent worker =================
  const int w = bid - 32;     // 0..191
  u16 (*At)[72] = reinterpret_cast<u16(*)[72]>(smem);            // 128 x 72
  u16 (*Bt)[72] = reinterpret_cast<u16(*)[72]>(smem + 18432);    // 256 x 72
  float* red = reinterpret_cast<float*>(smem + 55296);           // [2][64][4][2]
  const u16* Wb = reinterpret_cast<const u16*>(ws + OFF_WB);
  const int wm = wid & 1, wn = wid >> 1;
  const int sr = tid >> 3, ss = tid & 7;

  // ---- GEMM + per-chunk logsumexp, rt-major grid-stride ----
  for (int tl = w; tl < 4000; tl += 192) {
    const int rt = tl / 125, ct = tl % 125;
    const int row0 = rt * 128, col0 = ct * 256;

    f32x4 acc[4][4];
    #pragma unroll
    for (int i = 0; i < 4; ++i)
      #pragma unroll
      for (int j = 0; j < 4; ++j) acc[i][j] = {0, 0, 0, 0};

    for (int kt = 0; kt < 8; ++kt) {
      // stage At (hs rows, poll for validity)
      #pragma unroll
      for (int it = 0; it < 2; ++it) {
        int r = it * 64 + sr;
        const u32* p = hsu + (size_t)(row0 + r) * 256 + kt * 32 + ss * 4;
        u32 a0 = aload(p), a1 = aload(p + 1), a2 = aload(p + 2), a3 = aload(p + 3);
        int guard = 0;
        while ((a0 == POISON || a1 == POISON || a2 == POISON || a3 == POISON) && ++guard <= GUARD) {
          __builtin_amdgcn_s_sleep(64);
          a0 = aload(p); a1 = aload(p + 1); a2 = aload(p + 2); a3 = aload(p + 3);
        }
        u32* d = reinterpret_cast<u32*>(&At[r][ss * 8]);
        d[0] = a0; d[1] = a1; d[2] = a2; d[3] = a3;
      }
      // stage Bt (weights, no poll)
      #pragma unroll
      for (int it = 0; it < 4; ++it) {
        int r = it * 64 + sr;
        *reinterpret_cast<s16x8*>(&Bt[r][ss * 8]) =
            *reinterpret_cast<const s16x8*>(Wb + (size_t)(col0 + r) * H + kt * 64 + ss * 8);
      }
      __syncthreads();
      #pragma unroll
      for (int ks = 0; ks < 2; ++ks) {
        int kk = ks * 32 + lhi * 8;
        s16x8 af[4], bf[4];
        #pragma unroll
        for (int mi = 0; mi < 4; ++mi)
          af[mi] = *reinterpret_cast<const s16x8*>(&At[wm * 64 + mi * 16 + l15][kk]);
        #pragma unroll
        for (int ni = 0; ni < 4; ++ni)
          bf[ni] = *reinterpret_cast<const s16x8*>(&Bt[wn * 64 + ni * 16 + l15][kk]);
        #pragma unroll
        for (int mi = 0; mi < 4; ++mi)
          #pragma unroll
          for (int ni = 0; ni < 4; ++ni)
            acc[mi][ni] = __builtin_amdgcn_mfma_f32_16x16x32_bf16(af[mi], bf[ni], acc[mi][ni], 0, 0, 0);
      }
      __syncthreads();
    }

    float bias[4];
    #pragma unroll
    for (int ni = 0; ni < 4; ++ni) bias[ni] = out_b[col0 + wn * 64 + ni * 16 + l15];

    #pragma unroll
    for (int mi = 0; mi < 4; ++mi) {
      #pragma unroll
      for (int reg = 0; reg < 4; ++reg) {
        float l0 = acc[mi][0][reg] + bias[0];
        float l1 = acc[mi][1][reg] + bias[1];
        float l2 = acc[mi][2][reg] + bias[2];
        float l3 = acc[mi][3][reg] + bias[3];
        float m = fmaxf(fmaxf(l0, l1), fmaxf(l2, l3));
        for (int d = 1; d < 16; d <<= 1) m = fmaxf(m, __shfl_xor(m, d, 16));
        float s = __expf(l0 - m) + __expf(l1 - m) + __expf(l2 - m) + __expf(l3 - m);
        for (int d = 1; d < 16; d <<= 1) s += __shfl_xor(s, d, 16);
        if (l15 == 0) {
          int lr = mi * 16 + lhi * 4 + reg;
          red[((wm * 64 + lr) * 4 + wn) * 2 + 0] = m;
          red[((wm * 64 + lr) * 4 + wn) * 2 + 1] = s;
        }
      }
    }
    __syncthreads();
    if (tid < 128) {
      int lr = tid;
      float M = -3.0e38f, S = 0.f;
      #pragma unroll
      for (int wnn = 0; wnn < 4; ++wnn) {
        float m = red[(lr * 4 + wnn) * 2 + 0];
        float s = red[(lr * 4 + wnn) * 2 + 1];
        float nm = fmaxf(M, m);
        S = S * __expf(M - nm) + s * __expf(m - nm);
        M = nm;
      }
      // CEP [chunk][row]: contiguous 128-row writes (coalesced)
      u32* cepw = reinterpret_cast<u32*>(ws + OFF_CEP);
      size_t ix = ((size_t)ct * 4096 + row0 + lr) * 2;
      afstore(cepw + ix + 0, M);
      afstore(cepw + ix + 1, S);
    }
    __syncthreads();
  }

  // ---- ly: exact logit at target (one wave per row, grid-stride) ----
  for (int r = w * 8 + wid; r < 4096; r += 192 * 8) {
    int t = r >> 5, b = r & 31;
    int yy = y[b * T + t];
    const u32* hp = hsu + (size_t)r * 256 + lane * 4;
    u32 a0 = aload(hp), a1 = aload(hp + 1), a2 = aload(hp + 2), a3 = aload(hp + 3);
    int guard = 0;
    while ((a0 == POISON || a1 == POISON || a2 == POISON || a3 == POISON) && ++guard <= GUARD) {
      __builtin_amdgcn_s_sleep(64);
      a0 = aload(hp); a1 = aload(hp + 1); a2 = aload(hp + 2); a3 = aload(hp + 3);
    }
    const float4* wp = reinterpret_cast<const float4*>(out_W + (size_t)yy * H + lane * 8);
    float4 w0 = wp[0], w1 = wp[1];
    float s = b2f((u16)(a0 & 0xFFFF)) * w0.x + b2f((u16)(a0 >> 16)) * w0.y
            + b2f((u16)(a1 & 0xFFFF)) * w0.z + b2f((u16)(a1 >> 16)) * w0.w
            + b2f((u16)(a2 & 0xFFFF)) * w1.x + b2f((u16)(a2 >> 16)) * w1.y
            + b2f((u16)(a3 & 0xFFFF)) * w1.z + b2f((u16)(a3 >> 16)) * w1.w;
    for (int d = 1; d < 64; d <<= 1) s += __shfl_xor(s, d);
    if (lane == 0)
      afstore(reinterpret_cast<u32*>(ws + OFF_LGY) + r, s + out_b[yy]);
  }

  // ---- f1: combine chunks -> per-row CE (workers 0..7, one row/thread) ----
  {
    int r = w * 512 + tid;
    if (r < 4096) {
      const u32* lgyu = reinterpret_cast<const u32*>(ws + OFF_LGY);
      u32 lb = aload(lgyu + r);
      int guard = 0;
      while (lb == POISON && ++guard <= GUARD) { __builtin_amdgcn_s_sleep(64); lb = aload(lgyu + r); }
      float ly = __builtin_bit_cast(float, lb);
      const u32* cp = reinterpret_cast<const u32*>(ws + OFF_CEP);
      float M = -3.0e38f, S = 0.f;
      for (int cch = 0; cch < 125; ++cch) {
        size_t ix = ((size_t)cch * 4096 + r) * 2;
        u32 ma = aload(cp + ix), sa = aload(cp + ix + 1);
        int g2 = 0;
        while ((ma == POISON || sa == POISON) && ++g2 <= GUARD) {
          __builtin_amdgcn_s_sleep(64);
          ma = aload(cp + ix); sa = aload(cp + ix + 1);
        }
        float m = __builtin_bit_cast(float, ma), s = __builtin_bit_cast(float, sa);
        float nm = fmaxf(M, m);
        S = S * __expf(M - nm) + s * __expf(m - nm);
        M = nm;
      }
      afstore(reinterpret_cast<u32*>(ws + OFF_CER) + r, M + logf(S) - ly);
    }
  }

  // ---- f2: final reduction (worker 0 only) ----
  if (w == 0) {
    __syncthreads();
    float* rb = reinterpret_cast<float*>(smem);
    const u32* ceru = reinterpret_cast<const u32*>(ws + OFF_CER);
    const float* klp = reinterpret_cast<const float*>(ws + OFF_KLP);
    float s = 0.f;
    for (int j = 0; j < 8; ++j) {
      int r = tid + j * 512;
      u32 v = aload(ceru + r);
      int guard = 0;
      while (v == POISON && ++guard <= GUARD) { __builtin_amdgcn_s_sleep(64); v = aload(ceru + r); }
      s += __builtin_bit_cast(float, v);
    }
    if (tid < 64) s += klp[tid];
    rb[tid] = s;
    __syncthreads();
    for (int d = 256; d > 0; d >>= 1) {
      if (tid < d) rb[tid] += rb[tid + d];
      __syncthreads();
    }
    if (tid == 0) out[0] = rb[0] / 32.f;
  }
}

extern "C" void kernel_launch(void* const* d_in, const int* in_sizes, int n_in,
                              void* d_out, int out_size, void* d_ws, size_t ws_size,
                              hipStream_t stream) {
  (void)in_sizes; (void)n_in; (void)out_size; (void)ws_size;
  const int*   x       = (const int*)d_in[0];
  const int*   y       = (const int*)d_in[1];
  const float* epsv    = (const float*)d_in[2];
  const float* enc_emb = (const float*)d_in[3];
  const float* dec_emb = (const float*)d_in[4];
  const float* fWih    = (const float*)d_in[5];
  const float* fWhh    = (const float*)d_in[6];
  const float* fb      = (const float*)d_in[7];
  const float* bWih    = (const float*)d_in[8];
  const float* bWhh    = (const float*)d_in[9];
  const float* bb      = (const float*)d_in[10];
  const float* dWih    = (const float*)d_in[11];
  const float* dWhh    = (const float*)d_in[12];
  const float* db      = (const float*)d_in[13];
  const float* enc_hW  = (const float*)d_in[14];
  const float* enc_hb  = (const float*)d_in[15];
  const float* mu_W    = (const float*)d_in[16];
  const float* mu_b    = (const float*)d_in[17];
  const float* std_W   = (const float*)d_in[18];
  const float* std_b   = (const float*)d_in[19];
  const float* dec_hW  = (const float*)d_in[20];
  const float* dec_hb  = (const float*)d_in[21];
  const float* out_W   = (const float*)d_in[22];
  const float* out_b   = (const float*)d_in[23];
  char* ws = (char*)d_ws;

  // per-launch state: zero initial h slots; poison all dataflow buffers
  hipMemsetAsync(ws + OFF_ZF, 0x00, 65536, stream);
  hipMemsetAsync(ws + OFF_PF, 0xFF, OFF_PEND - OFF_PF, stream);

  phaseA_k<<<192, 512, 0, stream>>>(x, enc_emb, fWih, fWhh, fb, bWih, bWhh, bb,
                                    enc_hW, enc_hb, mu_W, mu_b, std_W, std_b,
                                    epsv, out_W, ws);

  // re-poison the CEP overlay (aliases enc fwd h-slots; stream-ordered after phaseA)
  hipMemsetAsync(ws + OFF_CEP, 0xFF, 4096000, stream);

  phaseB_k<<<224, 512, 0, stream>>>(x, y, dec_emb, dWih, dWhh, db, dec_hW, dec_hb,
                                    out_W, out_b, ws, (float*)d_out);
}